// Round 8
// baseline (1122.605 us; speedup 1.0000x reference)
//
#include <hip/hip_runtime.h>
#include <math.h>

#define NN 100000
#define NE 800000
// DIM=128, HEADS=4, CH=32

typedef __attribute__((ext_vector_type(8))) short short8;
typedef __attribute__((ext_vector_type(4))) float f32x4;

__device__ __forceinline__ float bf2f(unsigned short u) {
  union { float f; unsigned int i; } x; x.i = ((unsigned int)u) << 16; return x.f;
}
__device__ __forceinline__ unsigned short f2bf(float f) {
  union { float f; unsigned int i; } x; x.f = f;
  unsigned int r = x.i + 0x7fffu + ((x.i >> 16) & 1u);
  return (unsigned short)(r >> 16);
}

__device__ __forceinline__ short8 load8_f32_as_bf16(const float* p) {
  const float4 a = *(const float4*)p;
  const float4 b = *(const float4*)(p + 4);
  short8 r;
  r[0] = (short)f2bf(a.x); r[1] = (short)f2bf(a.y); r[2] = (short)f2bf(a.z); r[3] = (short)f2bf(a.w);
  r[4] = (short)f2bf(b.x); r[5] = (short)f2bf(b.y); r[6] = (short)f2bf(b.z); r[7] = (short)f2bf(b.w);
  return r;
}

// ================= CSR build =================
__global__ __launch_bounds__(256) void hist_k(const int* __restrict__ ei, int* __restrict__ deg) {
  int t = blockIdx.x * 256 + threadIdx.x;
  if (t < NE) atomicAdd(&deg[ei[NE + t]], 1);
}

__global__ __launch_bounds__(256) void scan1(const int* __restrict__ deg, int* __restrict__ bsum) {
  __shared__ int sd[256];
  const int b = blockIdx.x, t = threadIdx.x, base = b * 1024;
  int s = 0;
  #pragma unroll
  for (int i = 0; i < 4; i++) { int idx = base + t * 4 + i; if (idx < NN) s += deg[idx]; }
  sd[t] = s; __syncthreads();
  for (int off = 128; off >= 1; off >>= 1) { if (t < off) sd[t] += sd[t + off]; __syncthreads(); }
  if (t == 0) bsum[b] = sd[0];
}

__global__ void scan2(int* __restrict__ bsum, int nb, int* __restrict__ rowstart) {
  if (threadIdx.x == 0 && blockIdx.x == 0) {
    int run = 0;
    for (int i = 0; i < nb; i++) { int v = bsum[i]; bsum[i] = run; run += v; }
    rowstart[NN] = run;
  }
}

__global__ __launch_bounds__(256) void scan3(const int* __restrict__ deg, const int* __restrict__ bsum,
                                             int* __restrict__ rowstart, int* __restrict__ cursor) {
  __shared__ int sd[256];
  const int b = blockIdx.x, t = threadIdx.x, base = b * 1024;
  int vals[4]; int s = 0;
  #pragma unroll
  for (int i = 0; i < 4; i++) { int idx = base + t * 4 + i; vals[i] = (idx < NN) ? deg[idx] : 0; s += vals[i]; }
  sd[t] = s; __syncthreads();
  int excl = 0;
  for (int i = 0; i < t; i++) excl += sd[i];
  int run = bsum[b] + excl;
  #pragma unroll
  for (int i = 0; i < 4; i++) {
    int idx = base + t * 4 + i;
    if (idx < NN) { rowstart[idx] = run; cursor[idx] = run; run += vals[i]; }
  }
}

__global__ __launch_bounds__(256) void scatter_k(const int* __restrict__ ei, int* __restrict__ cursor,
                                                 int2* __restrict__ rec) {
  int t = blockIdx.x * 256 + threadIdx.x;
  if (t >= NE) return;
  int dst = ei[NE + t];
  int pos = atomicAdd(&cursor[dst], 1);
  rec[pos] = make_int2(ei[t], t);   // {src, edge_id}
}

// ================= weight prep =================
// slots: 0..3 = Wq0,Wk0,Wv0,Ws0 ; 4..7 = Wq1,Wk1,Wv1,Ws1 ; 8,9 = We0,We1 ; 10 = Wo
__global__ __launch_bounds__(256) void conv_w(
    const float* __restrict__ Wq, const float* __restrict__ Wk, const float* __restrict__ Wv,
    const float* __restrict__ Ws, const float* __restrict__ We, const float* __restrict__ Wo,
    unsigned short* __restrict__ wT)
{
  int idx = blockIdx.x * 256 + threadIdx.x;   // 11*16384 total
  int m = idx >> 14;
  int r = idx & 16383;
  int n = r >> 7, kk = r & 127;
  const float* src;
  switch (m) {
    case 0: src = Wq; break;
    case 1: src = Wk; break;
    case 2: src = Wv; break;
    case 3: src = Ws; break;
    case 4: src = Wq + 16384; break;
    case 5: src = Wk + 16384; break;
    case 6: src = Wv + 16384; break;
    case 7: src = Ws + 16384; break;
    case 8: src = We; break;
    case 9: src = We + 16384; break;
    default: src = Wo; break;
  }
  wT[idx] = f2bf(src[(size_t)kk * 128 + n]);
}

// ================= register-weight GEMM, swapped-operand MFMA =================
// C = A[M,128] @ wT[slot] (+bias), bf16 out, coalesced row-order stores.
// block = 8 waves x 128 rows; each wave owns 16 cols; weights live in VGPRs.
// Swapped mfma(wfrag, afrag, acc): lane holds row=lane&15, cols=(lane>>4)*4+j.
template<int ABF16, int HASBIAS, int NMAT>
__global__ __launch_bounds__(512, 4) void gemm_rs(
    const void* __restrict__ Ap, const unsigned short* __restrict__ wT, int s0, int s1,
    const float* __restrict__ bias0, const float* __restrict__ bias1,
    unsigned short* __restrict__ o0, unsigned short* __restrict__ o1, int M)
{
  const int wave = threadIdx.x >> 6, lane = threadIdx.x & 63;
  const int l15 = lane & 15, g = lane >> 4;
  const int colf = wave * 16;
  const int rb = blockIdx.x * 128;

  // --- preload weight fragments into registers (once) ---
  short8 wf[NMAT][4];
  const int slots[2] = { s0, s1 };
  #pragma unroll
  for (int m = 0; m < NMAT; ++m) {
    const unsigned short* wp = wT + (size_t)slots[m] * 16384;
    const int col = colf + l15;
    #pragma unroll
    for (int kt = 0; kt < 4; ++kt)
      wf[m][kt] = *(const short8*)(wp + (size_t)col * 128 + kt * 32 + g * 8);
  }
  float bia[NMAT][4];
  if (HASBIAS) {
    const float* bp[2] = { bias0, bias1 };
    #pragma unroll
    for (int m = 0; m < NMAT; ++m)
      #pragma unroll
      for (int j = 0; j < 4; ++j)
        bia[m][j] = bp[m][colf + g * 4 + j];
  }

  // --- prefetch first row-group ---
  short8 a_cur[4], a_nxt[4];
  {
    const int r = rb + l15;
    const int ar = (r < M) ? r : (M - 1);
    #pragma unroll
    for (int kt = 0; kt < 4; ++kt) {
      if (ABF16) a_cur[kt] = *(const short8*)((const unsigned short*)Ap + (size_t)ar * 128 + kt * 32 + g * 8);
      else       a_cur[kt] = load8_f32_as_bf16((const float*)Ap + (size_t)ar * 128 + kt * 32 + g * 8);
    }
  }
  #pragma unroll
  for (int kt = 0; kt < 4; ++kt) a_nxt[kt] = a_cur[kt];

  #pragma unroll
  for (int rg = 0; rg < 8; ++rg) {
    if (rg < 7) {
      const int rn = rb + (rg + 1) * 16 + l15;
      const int arn = (rn < M) ? rn : (M - 1);
      #pragma unroll
      for (int kt = 0; kt < 4; ++kt) {
        if (ABF16) a_nxt[kt] = *(const short8*)((const unsigned short*)Ap + (size_t)arn * 128 + kt * 32 + g * 8);
        else       a_nxt[kt] = load8_f32_as_bf16((const float*)Ap + (size_t)arn * 128 + kt * 32 + g * 8);
      }
    }

    f32x4 accs[NMAT];
    #pragma unroll
    for (int m = 0; m < NMAT; ++m) {
      f32x4 acc; acc[0] = 0.f; acc[1] = 0.f; acc[2] = 0.f; acc[3] = 0.f;
      #pragma unroll
      for (int kt = 0; kt < 4; ++kt)
        acc = __builtin_amdgcn_mfma_f32_16x16x32_bf16(wf[m][kt], a_cur[kt], acc, 0, 0, 0);
      accs[m] = acc;
    }

    const int r = rb + rg * 16 + l15;
    if (r < M) {
      #pragma unroll
      for (int m = 0; m < NMAT; ++m) {
        unsigned short* op = (m == 0) ? o0 : o1;
        f32x4 acc = accs[m];
        float f0 = acc[0], f1 = acc[1], f2 = acc[2], f3 = acc[3];
        if (HASBIAS) { f0 += bia[m][0]; f1 += bia[m][1]; f2 += bia[m][2]; f3 += bia[m][3]; }
        uint2 pk;
        pk.x = (unsigned int)f2bf(f0) | ((unsigned int)f2bf(f1) << 16);
        pk.y = (unsigned int)f2bf(f2) | ((unsigned int)f2bf(f3) << 16);
        *(uint2*)(op + (size_t)r * 128 + colf + g * 4) = pk;
      }
    }
    #pragma unroll
    for (int kt = 0; kt < 4; ++kt) a_cur[kt] = a_nxt[kt];
  }
}

// ================= final GEMM + gate epilogue (f32 out), 64 rows/block =================
__global__ __launch_bounds__(256, 3) void final_rs(
    const unsigned short* __restrict__ A, const unsigned short* __restrict__ wp,
    const float* __restrict__ bo, const float* __restrict__ xin,
    const float* __restrict__ gate, float* __restrict__ out, int M)
{
  const int wave = threadIdx.x >> 6, lane = threadIdx.x & 63;
  const int l15 = lane & 15, g = lane >> 4;
  const int colf = wave * 32;
  const int rb = blockIdx.x * 64;

  short8 wf[2][4];
  #pragma unroll
  for (int cb = 0; cb < 2; ++cb) {
    const int col = colf + cb * 16 + l15;
    #pragma unroll
    for (int kt = 0; kt < 4; ++kt)
      wf[cb][kt] = *(const short8*)(wp + (size_t)col * 128 + kt * 32 + g * 8);
  }
  float bia[2][4];
  #pragma unroll
  for (int cb = 0; cb < 2; ++cb)
    #pragma unroll
    for (int j = 0; j < 4; ++j)
      bia[cb][j] = bo[colf + cb * 16 + g * 4 + j];

  #pragma unroll
  for (int rg = 0; rg < 4; ++rg) {
    const int r = rb + rg * 16 + l15;
    const int ar = (r < M) ? r : (M - 1);
    short8 a[4];
    #pragma unroll
    for (int kt = 0; kt < 4; ++kt)
      a[kt] = *(const short8*)(A + (size_t)ar * 128 + kt * 32 + g * 8);

    f32x4 accs[2];
    #pragma unroll
    for (int cb = 0; cb < 2; ++cb) {
      f32x4 acc; acc[0] = 0.f; acc[1] = 0.f; acc[2] = 0.f; acc[3] = 0.f;
      #pragma unroll
      for (int kt = 0; kt < 4; ++kt)
        acc = __builtin_amdgcn_mfma_f32_16x16x32_bf16(wf[cb][kt], a[kt], acc, 0, 0, 0);
      accs[cb] = acc;
    }

    if (r < M) {
      const float gr = gate[r];
      #pragma unroll
      for (int cb = 0; cb < 2; ++cb) {
        const int c0 = colf + cb * 16 + g * 4;
        const float4 xv = *(const float4*)(xin + (size_t)r * 128 + c0);
        float4 res;
        res.x = gr * xv.x + (1.f - gr) * (accs[cb][0] + bia[cb][0]);
        res.y = gr * xv.y + (1.f - gr) * (accs[cb][1] + bia[cb][1]);
        res.z = gr * xv.z + (1.f - gr) * (accs[cb][2] + bia[cb][2]);
        res.w = gr * xv.w + (1.f - gr) * (accs[cb][3] + bia[cb][3]);
        *(float4*)(out + (size_t)r * 128 + c0) = res;
      }
    }
  }
}

// ================= fused CSR attention + node epilogue =================
// e stays in edge order; rec[pos] = {src, edge_id} sorted by dst.
__global__ __launch_bounds__(256) void csr_attn(
    const int* __restrict__ rowstart, const int2* __restrict__ rec,
    const unsigned short* __restrict__ e,
    const unsigned short* __restrict__ q, const unsigned short* __restrict__ k,
    const unsigned short* __restrict__ v, const unsigned short* __restrict__ xr,
    const float* __restrict__ Wb, const float* __restrict__ lng, const float* __restrict__ lnb,
    const unsigned short* __restrict__ prev, unsigned short* __restrict__ hout)
{
  const int n = blockIdx.x * 4 + (threadIdx.x >> 6);
  if (n >= NN) return;
  const int lane = threadIdx.x & 63;
  const int d0 = lane * 2;
  const size_t base = (size_t)n * 128 + d0;

  const unsigned int qp = *(const unsigned int*)(q + base);
  const float q0 = bf2f(qp & 0xffff), q1 = bf2f(qp >> 16);

  float acc0 = 0.f, acc1 = 0.f, den = 0.f;
  const int s = rowstart[n], eend = rowstart[n + 1];
  const float scale = 0.17677669529663687f;   // 1/sqrt(32)

  int pos = s;
  for (; pos + 1 < eend; pos += 2) {
    const int2 rA = rec[pos], rB = rec[pos + 1];
    const unsigned int kpA = *(const unsigned int*)(k + (size_t)rA.x * 128 + d0);
    const unsigned int epA = *(const unsigned int*)(e + (size_t)rA.y * 128 + d0);
    const unsigned int vpA = *(const unsigned int*)(v + (size_t)rA.x * 128 + d0);
    const unsigned int kpB = *(const unsigned int*)(k + (size_t)rB.x * 128 + d0);
    const unsigned int epB = *(const unsigned int*)(e + (size_t)rB.y * 128 + d0);
    const unsigned int vpB = *(const unsigned int*)(v + (size_t)rB.x * 128 + d0);

    const float eA0 = bf2f(epA & 0xffff), eA1 = bf2f(epA >> 16);
    const float eB0 = bf2f(epB & 0xffff), eB1 = bf2f(epB >> 16);
    float dotA = q0 * (bf2f(kpA & 0xffff) + eA0) + q1 * (bf2f(kpA >> 16) + eA1);
    float dotB = q0 * (bf2f(kpB & 0xffff) + eB0) + q1 * (bf2f(kpB >> 16) + eB1);
    dotA += __shfl_xor(dotA, 1, 64); dotB += __shfl_xor(dotB, 1, 64);
    dotA += __shfl_xor(dotA, 2, 64); dotB += __shfl_xor(dotB, 2, 64);
    dotA += __shfl_xor(dotA, 4, 64); dotB += __shfl_xor(dotB, 4, 64);
    dotA += __shfl_xor(dotA, 8, 64); dotB += __shfl_xor(dotB, 8, 64);
    const float pA = expf(dotA * scale);
    const float pB = expf(dotB * scale);
    acc0 += pA * (bf2f(vpA & 0xffff) + eA0) + pB * (bf2f(vpB & 0xffff) + eB0);
    acc1 += pA * (bf2f(vpA >> 16) + eA1) + pB * (bf2f(vpB >> 16) + eB1);
    den  += pA + pB;
  }
  if (pos < eend) {
    const int2 rA = rec[pos];
    const unsigned int kpA = *(const unsigned int*)(k + (size_t)rA.x * 128 + d0);
    const unsigned int epA = *(const unsigned int*)(e + (size_t)rA.y * 128 + d0);
    const unsigned int vpA = *(const unsigned int*)(v + (size_t)rA.x * 128 + d0);
    const float eA0 = bf2f(epA & 0xffff), eA1 = bf2f(epA >> 16);
    float dotA = q0 * (bf2f(kpA & 0xffff) + eA0) + q1 * (bf2f(kpA >> 16) + eA1);
    dotA += __shfl_xor(dotA, 1, 64);
    dotA += __shfl_xor(dotA, 2, 64);
    dotA += __shfl_xor(dotA, 4, 64);
    dotA += __shfl_xor(dotA, 8, 64);
    const float pA = expf(dotA * scale);
    acc0 += pA * (bf2f(vpA & 0xffff) + eA0);
    acc1 += pA * (bf2f(vpA >> 16) + eA1);
    den  += pA;
  }

  const float dinv = 1.f / (den + 1e-16f);
  const float o0 = acc0 * dinv, o1 = acc1 * dinv;

  const float x0 = bf2f(xr[base]), x1 = bf2f(xr[base + 1]);
  float sb = o0 * Wb[d0] + o1 * Wb[d0 + 1]
           + x0 * Wb[128 + d0] + x1 * Wb[129 + d0]
           + (o0 - x0) * Wb[256 + d0] + (o1 - x1) * Wb[257 + d0];
  #pragma unroll
  for (int off = 32; off >= 1; off >>= 1) sb += __shfl_xor(sb, off, 64);
  const float beta = 1.f / (1.f + expf(-sb));

  float y0 = beta * x0 + (1.f - beta) * o0;
  float y1 = beta * x1 + (1.f - beta) * o1;
  y0 = 0.5f * y0 * (1.f + erff(y0 * 0.7071067811865475f));
  y1 = 0.5f * y1 * (1.f + erff(y1 * 0.7071067811865475f));

  float mu = y0 + y1;
  #pragma unroll
  for (int off = 32; off >= 1; off >>= 1) mu += __shfl_xor(mu, off, 64);
  mu *= (1.f / 128.f);
  float dv0 = y0 - mu, dv1 = y1 - mu;
  float var = dv0 * dv0 + dv1 * dv1;
  #pragma unroll
  for (int off = 32; off >= 1; off >>= 1) var += __shfl_xor(var, off, 64);
  var *= (1.f / 128.f);
  const float rs = rsqrtf(var + 1e-5f);

  float h0 = dv0 * rs * lng[d0] + lnb[d0];
  float h1 = dv1 * rs * lng[d0 + 1] + lnb[d0 + 1];
  if (prev) { h0 += bf2f(prev[base]); h1 += bf2f(prev[base + 1]); }
  unsigned int packed = (unsigned int)f2bf(h0) | ((unsigned int)f2bf(h1) << 16);
  *(unsigned int*)(hout + base) = packed;
}

// ================= gate =================
__global__ __launch_bounds__(256) void gate_kernel(
    const float* __restrict__ x, const float* __restrict__ Wg,
    const float* __restrict__ bg, float* __restrict__ g)
{
  const int row = blockIdx.x * 4 + (threadIdx.x >> 6);
  const int lane = threadIdx.x & 63;
  const size_t base = (size_t)row * 128 + lane * 2;
  float s = x[base] * Wg[lane * 2] + x[base + 1] * Wg[lane * 2 + 1];
  #pragma unroll
  for (int off = 32; off >= 1; off >>= 1) s += __shfl_xor(s, off, 64);
  g[row] = 1.f / (1.f + expf(-(s + bg[0])));
}

extern "C" void kernel_launch(void* const* d_in, const int* in_sizes, int n_in,
                              void* d_out, int out_size, void* d_ws, size_t ws_size,
                              hipStream_t stream)
{
  const float* x  = (const float*)d_in[0];
  const int*   ei = (const int*)d_in[1];
  const float* ea = (const float*)d_in[2];
  const float* Wq = (const float*)d_in[3];
  const float* bq = (const float*)d_in[4];
  const float* Wk = (const float*)d_in[5];
  const float* bk = (const float*)d_in[6];
  const float* Wv = (const float*)d_in[7];
  const float* bv = (const float*)d_in[8];
  const float* We = (const float*)d_in[9];
  const float* Ws = (const float*)d_in[10];
  const float* bs = (const float*)d_in[11];
  const float* Wb = (const float*)d_in[12];
  const float* lng= (const float*)d_in[13];
  const float* lnb= (const float*)d_in[14];
  const float* Wo = (const float*)d_in[15];
  const float* bo = (const float*)d_in[16];
  const float* Wg = (const float*)d_in[17];
  const float* bg = (const float*)d_in[18];
  float* outp = (float*)d_out;

  char* p = (char*)d_ws;
  auto take = [&](size_t b) -> char* { char* r = p; p += (b + 255) & ~(size_t)255; return r; };
  unsigned short* wT = (unsigned short*)take((size_t)11 * 16384 * 2);
  unsigned short* q  = (unsigned short*)take((size_t)NN * 128 * 2);
  unsigned short* k  = (unsigned short*)take((size_t)NN * 128 * 2);
  unsigned short* v  = (unsigned short*)take((size_t)NN * 128 * 2);
  unsigned short* xr = (unsigned short*)take((size_t)NN * 128 * 2);
  unsigned short* h1 = (unsigned short*)take((size_t)NN * 128 * 2);
  unsigned short* hs = (unsigned short*)take((size_t)NN * 128 * 2);
  float* gbuf = (float*)take((size_t)NN * 4);
  int* deg      = (int*)take((size_t)NN * 4);
  int* rowstart = (int*)take((size_t)(NN + 1) * 4);
  int* cursor   = (int*)take((size_t)NN * 4);
  int* bsum     = (int*)take((size_t)128 * 4);
  int2* rec     = (int2*)take((size_t)NE * 8);
  unsigned short* e0 = (unsigned short*)take((size_t)NE * 128 * 2);
  size_t used = (size_t)(p - (char*)d_ws);
  const bool dual = (used + (size_t)NE * 128 * 2) <= ws_size;
  unsigned short* e1 = dual ? (unsigned short*)take((size_t)NE * 128 * 2) : e0;

  const int SCAN_BLOCKS = (NN + 1023) / 1024;   // 98
  const int NTILE_E  = (NE + 127) / 128;        // 6250   (gemm_rs: 128 rows/block)
  const int NTILE_N  = (NN + 127) / 128;        // 782    (gemm_rs: 128 rows/block)
  const int NTILE_N64 = (NN + 63) / 64;         // 1563   (final_rs: 64 rows/block)

  // ---- CSR build ----
  hipMemsetAsync(deg, 0, (size_t)NN * 4, stream);
  hist_k<<<(NE + 255) / 256, 256, 0, stream>>>(ei, deg);
  scan1<<<SCAN_BLOCKS, 256, 0, stream>>>(deg, bsum);
  scan2<<<1, 64, 0, stream>>>(bsum, SCAN_BLOCKS, rowstart);
  scan3<<<SCAN_BLOCKS, 256, 0, stream>>>(deg, bsum, rowstart, cursor);
  scatter_k<<<(NE + 255) / 256, 256, 0, stream>>>(ei, cursor, rec);

  // ---- weights + edge projection (coalesced, edge order) ----
  conv_w<<<704, 256, 0, stream>>>(Wq, Wk, Wv, Ws, We, Wo, wT);
  if (dual) {
    gemm_rs<0,0,2><<<NTILE_E, 512, 0, stream>>>(ea, wT, 8, 9, nullptr, nullptr, e0, e1, NE);
  } else {
    gemm_rs<0,0,1><<<NTILE_E, 512, 0, stream>>>(ea, wT, 8, 8, nullptr, nullptr, e0, e0, NE);
  }

  // ---- layer 1 ----
  gemm_rs<0,1,2><<<NTILE_N, 512, 0, stream>>>(x, wT, 0, 1, bq, bk, q, k, NN);
  gemm_rs<0,1,2><<<NTILE_N, 512, 0, stream>>>(x, wT, 2, 3, bv, bs, v, xr, NN);
  csr_attn<<<25000, 256, 0, stream>>>(rowstart, rec, e0, q, k, v, xr, Wb, lng, lnb, nullptr, h1);

  // ---- layer 2 ----
  if (!dual) gemm_rs<0,0,1><<<NTILE_E, 512, 0, stream>>>(ea, wT, 9, 9, nullptr, nullptr, e0, e0, NE);
  gemm_rs<1,1,2><<<NTILE_N, 512, 0, stream>>>(h1, wT, 4, 5, bq + 128, bk + 128, q, k, NN);
  gemm_rs<1,1,2><<<NTILE_N, 512, 0, stream>>>(h1, wT, 6, 7, bv + 128, bs + 128, v, xr, NN);
  csr_attn<<<25000, 256, 0, stream>>>(rowstart, rec, e1, q, k, v, xr, Wb + 384, lng + 128, lnb + 128, h1, hs);

  // ---- final ----
  gate_kernel<<<25000, 256, 0, stream>>>(x, Wg, bg, gbuf);
  final_rs<<<NTILE_N64, 256, 0, stream>>>(hs, wT + (size_t)10 * 16384, bo, x, gbuf, outp, NN);
}

// Round 9
// 788.023 us; speedup vs baseline: 1.4246x; 1.4246x over previous
//
#include <hip/hip_runtime.h>
#include <math.h>

#define NN 100000
#define NE 800000
// DIM=128, HEADS=4, CH=32

typedef __attribute__((ext_vector_type(8))) short short8;
typedef __attribute__((ext_vector_type(4))) float f32x4;

__device__ __forceinline__ float bf2f(unsigned short u) {
  union { float f; unsigned int i; } x; x.i = ((unsigned int)u) << 16; return x.f;
}
__device__ __forceinline__ unsigned short f2bf(float f) {
  union { float f; unsigned int i; } x; x.f = f;
  unsigned int r = x.i + 0x7fffu + ((x.i >> 16) & 1u);
  return (unsigned short)(r >> 16);
}

__device__ __forceinline__ short8 load8_f32_as_bf16(const float* p) {
  const float4 a = *(const float4*)p;
  const float4 b = *(const float4*)(p + 4);
  short8 r;
  r[0] = (short)f2bf(a.x); r[1] = (short)f2bf(a.y); r[2] = (short)f2bf(a.z); r[3] = (short)f2bf(a.w);
  r[4] = (short)f2bf(b.x); r[5] = (short)f2bf(b.y); r[6] = (short)f2bf(b.z); r[7] = (short)f2bf(b.w);
  return r;
}

// ================= CSR build =================
__global__ __launch_bounds__(256) void hist_k(const int* __restrict__ ei, int* __restrict__ deg) {
  int t = blockIdx.x * 256 + threadIdx.x;
  if (t < NE) atomicAdd(&deg[ei[NE + t]], 1);
}

__global__ __launch_bounds__(256) void scan1(const int* __restrict__ deg, int* __restrict__ bsum) {
  __shared__ int sd[256];
  const int b = blockIdx.x, t = threadIdx.x, base = b * 1024;
  int s = 0;
  #pragma unroll
  for (int i = 0; i < 4; i++) { int idx = base + t * 4 + i; if (idx < NN) s += deg[idx]; }
  sd[t] = s; __syncthreads();
  for (int off = 128; off >= 1; off >>= 1) { if (t < off) sd[t] += sd[t + off]; __syncthreads(); }
  if (t == 0) bsum[b] = sd[0];
}

__global__ void scan2(int* __restrict__ bsum, int nb, int* __restrict__ rowstart) {
  if (threadIdx.x == 0 && blockIdx.x == 0) {
    int run = 0;
    for (int i = 0; i < nb; i++) { int v = bsum[i]; bsum[i] = run; run += v; }
    rowstart[NN] = run;
  }
}

__global__ __launch_bounds__(256) void scan3(const int* __restrict__ deg, const int* __restrict__ bsum,
                                             int* __restrict__ rowstart, int* __restrict__ cursor) {
  __shared__ int sd[256];
  const int b = blockIdx.x, t = threadIdx.x, base = b * 1024;
  int vals[4]; int s = 0;
  #pragma unroll
  for (int i = 0; i < 4; i++) { int idx = base + t * 4 + i; vals[i] = (idx < NN) ? deg[idx] : 0; s += vals[i]; }
  sd[t] = s; __syncthreads();
  int excl = 0;
  for (int i = 0; i < t; i++) excl += sd[i];
  int run = bsum[b] + excl;
  #pragma unroll
  for (int i = 0; i < 4; i++) {
    int idx = base + t * 4 + i;
    if (idx < NN) { rowstart[idx] = run; cursor[idx] = run; run += vals[i]; }
  }
}

__global__ __launch_bounds__(256) void scatter_k(const int* __restrict__ ei, int* __restrict__ cursor,
                                                 int2* __restrict__ rec) {
  int t = blockIdx.x * 256 + threadIdx.x;
  if (t >= NE) return;
  int dst = ei[NE + t];
  int pos = atomicAdd(&cursor[dst], 1);
  rec[pos] = make_int2(ei[t], t);   // {src, edge_id}
}

// ================= weight prep =================
// slots: 0..3 = Wq0,Wk0,Wv0,Ws0 ; 4..7 = Wq1,Wk1,Wv1,Ws1 ; 8,9 = We0,We1 ; 10 = Wo
__global__ __launch_bounds__(256) void conv_w(
    const float* __restrict__ Wq, const float* __restrict__ Wk, const float* __restrict__ Wv,
    const float* __restrict__ Ws, const float* __restrict__ We, const float* __restrict__ Wo,
    unsigned short* __restrict__ wT)
{
  int idx = blockIdx.x * 256 + threadIdx.x;   // 11*16384 total
  int m = idx >> 14;
  int r = idx & 16383;
  int n = r >> 7, kk = r & 127;
  const float* src;
  switch (m) {
    case 0: src = Wq; break;
    case 1: src = Wk; break;
    case 2: src = Wv; break;
    case 3: src = Ws; break;
    case 4: src = Wq + 16384; break;
    case 5: src = Wk + 16384; break;
    case 6: src = Wv + 16384; break;
    case 7: src = Ws + 16384; break;
    case 8: src = We; break;
    case 9: src = We + 16384; break;
    default: src = Wo; break;
  }
  wT[idx] = f2bf(src[(size_t)kk * 128 + n]);
}

// ================= LDS-staged GEMM, register weights, swapped-operand MFMA =================
// C = A[M,128] @ wT[slot] (+bias), bf16 out, coalesced row-order stores.
// Block = 4 waves, 128-row tile. A staged cooperatively into LDS (bf16, 272B row
// stride), converted once. Wave owns 32 cols; weights live in VGPRs.
// Swapped mfma(wfrag, afrag, acc): lane holds row=lane&15, cols=(lane>>4)*4+j.
template<int ABF16, int HASBIAS, int NMAT>
__global__ __launch_bounds__(256, 2) void gemm_lds(
    const void* __restrict__ Ap, const unsigned short* __restrict__ wT, int s0, int s1,
    const float* __restrict__ bias0, const float* __restrict__ bias1,
    unsigned short* __restrict__ o0, unsigned short* __restrict__ o1, int M)
{
  __shared__ __align__(16) unsigned short As[128 * 136];   // 34.8 KB, 272B row stride
  const int wave = threadIdx.x >> 6, lane = threadIdx.x & 63;
  const int l15 = lane & 15, g = lane >> 4;
  const int colf = wave * 32;
  const int rb = blockIdx.x * 128;

  // --- preload weight fragments into registers (once) ---
  short8 wf[NMAT][2][4];
  const int slots[2] = { s0, s1 };
  #pragma unroll
  for (int m = 0; m < NMAT; ++m) {
    const unsigned short* wp = wT + (size_t)slots[m] * 16384;
    #pragma unroll
    for (int cb = 0; cb < 2; ++cb) {
      const int col = colf + cb * 16 + l15;
      #pragma unroll
      for (int kt = 0; kt < 4; ++kt)
        wf[m][cb][kt] = *(const short8*)(wp + (size_t)col * 128 + kt * 32 + g * 8);
    }
  }
  float bia[NMAT][2][4];
  if (HASBIAS) {
    const float* bp[2] = { bias0, bias1 };
    #pragma unroll
    for (int m = 0; m < NMAT; ++m)
      #pragma unroll
      for (int cb = 0; cb < 2; ++cb)
        #pragma unroll
        for (int j = 0; j < 4; ++j)
          bia[m][cb][j] = bp[m][colf + cb * 16 + g * 4 + j];
  }

  // --- cooperative stage: thread t -> row t&127, half t>>7 (64 cols) ---
  {
    const int r = threadIdx.x & 127;
    const int hf = threadIdx.x >> 7;
    const int gr = rb + r;
    const int ar = (gr < M) ? gr : (M - 1);
    unsigned short* dst = As + r * 136 + hf * 64;
    if (ABF16) {
      const unsigned short* srcp = (const unsigned short*)Ap + (size_t)ar * 128 + hf * 64;
      #pragma unroll
      for (int i = 0; i < 8; ++i)
        *(short8*)(dst + i * 8) = *(const short8*)(srcp + i * 8);
    } else {
      const float* srcp = (const float*)Ap + (size_t)ar * 128 + hf * 64;
      #pragma unroll
      for (int i = 0; i < 8; ++i)
        *(short8*)(dst + i * 8) = load8_f32_as_bf16(srcp + i * 8);
    }
  }
  __syncthreads();

  #pragma unroll
  for (int rg = 0; rg < 8; ++rg) {
    const int row = rg * 16 + l15;
    short8 a[4];
    #pragma unroll
    for (int kt = 0; kt < 4; ++kt)
      a[kt] = *(const short8*)(As + row * 136 + kt * 32 + g * 8);

    f32x4 accs[NMAT][2];
    #pragma unroll
    for (int m = 0; m < NMAT; ++m) {
      #pragma unroll
      for (int cb = 0; cb < 2; ++cb) {
        f32x4 acc; acc[0] = 0.f; acc[1] = 0.f; acc[2] = 0.f; acc[3] = 0.f;
        #pragma unroll
        for (int kt = 0; kt < 4; ++kt)
          acc = __builtin_amdgcn_mfma_f32_16x16x32_bf16(wf[m][cb][kt], a[kt], acc, 0, 0, 0);
        accs[m][cb] = acc;
      }
    }

    const int r = rb + rg * 16 + l15;
    if (r < M) {
      #pragma unroll
      for (int m = 0; m < NMAT; ++m) {
        unsigned short* op = (m == 0) ? o0 : o1;
        #pragma unroll
        for (int cb = 0; cb < 2; ++cb) {
          f32x4 acc = accs[m][cb];
          float f0 = acc[0], f1 = acc[1], f2 = acc[2], f3 = acc[3];
          if (HASBIAS) { f0 += bia[m][cb][0]; f1 += bia[m][cb][1]; f2 += bia[m][cb][2]; f3 += bia[m][cb][3]; }
          uint2 pk;
          pk.x = (unsigned int)f2bf(f0) | ((unsigned int)f2bf(f1) << 16);
          pk.y = (unsigned int)f2bf(f2) | ((unsigned int)f2bf(f3) << 16);
          *(uint2*)(op + (size_t)r * 128 + colf + cb * 16 + g * 4) = pk;
        }
      }
    }
  }
}

// ================= final GEMM + gate epilogue (f32 out), 64 rows/block =================
__global__ __launch_bounds__(256, 3) void final_rs(
    const unsigned short* __restrict__ A, const unsigned short* __restrict__ wp,
    const float* __restrict__ bo, const float* __restrict__ xin,
    const float* __restrict__ gate, float* __restrict__ out, int M)
{
  const int wave = threadIdx.x >> 6, lane = threadIdx.x & 63;
  const int l15 = lane & 15, g = lane >> 4;
  const int colf = wave * 32;
  const int rb = blockIdx.x * 64;

  short8 wf[2][4];
  #pragma unroll
  for (int cb = 0; cb < 2; ++cb) {
    const int col = colf + cb * 16 + l15;
    #pragma unroll
    for (int kt = 0; kt < 4; ++kt)
      wf[cb][kt] = *(const short8*)(wp + (size_t)col * 128 + kt * 32 + g * 8);
  }
  float bia[2][4];
  #pragma unroll
  for (int cb = 0; cb < 2; ++cb)
    #pragma unroll
    for (int j = 0; j < 4; ++j)
      bia[cb][j] = bo[colf + cb * 16 + g * 4 + j];

  #pragma unroll
  for (int rg = 0; rg < 4; ++rg) {
    const int r = rb + rg * 16 + l15;
    const int ar = (r < M) ? r : (M - 1);
    short8 a[4];
    #pragma unroll
    for (int kt = 0; kt < 4; ++kt)
      a[kt] = *(const short8*)(A + (size_t)ar * 128 + kt * 32 + g * 8);

    f32x4 accs[2];
    #pragma unroll
    for (int cb = 0; cb < 2; ++cb) {
      f32x4 acc; acc[0] = 0.f; acc[1] = 0.f; acc[2] = 0.f; acc[3] = 0.f;
      #pragma unroll
      for (int kt = 0; kt < 4; ++kt)
        acc = __builtin_amdgcn_mfma_f32_16x16x32_bf16(wf[cb][kt], a[kt], acc, 0, 0, 0);
      accs[cb] = acc;
    }

    if (r < M) {
      const float gr = gate[r];
      #pragma unroll
      for (int cb = 0; cb < 2; ++cb) {
        const int c0 = colf + cb * 16 + g * 4;
        const float4 xv = *(const float4*)(xin + (size_t)r * 128 + c0);
        float4 res;
        res.x = gr * xv.x + (1.f - gr) * (accs[cb][0] + bia[cb][0]);
        res.y = gr * xv.y + (1.f - gr) * (accs[cb][1] + bia[cb][1]);
        res.z = gr * xv.z + (1.f - gr) * (accs[cb][2] + bia[cb][2]);
        res.w = gr * xv.w + (1.f - gr) * (accs[cb][3] + bia[cb][3]);
        *(float4*)(out + (size_t)r * 128 + c0) = res;
      }
    }
  }
}

// ================= fused CSR attention + node epilogue =================
// e stays in edge order; rec[pos] = {src, edge_id} sorted by dst.
__global__ __launch_bounds__(256) void csr_attn(
    const int* __restrict__ rowstart, const int2* __restrict__ rec,
    const unsigned short* __restrict__ e,
    const unsigned short* __restrict__ q, const unsigned short* __restrict__ k,
    const unsigned short* __restrict__ v, const unsigned short* __restrict__ xr,
    const float* __restrict__ Wb, const float* __restrict__ lng, const float* __restrict__ lnb,
    const unsigned short* __restrict__ prev, unsigned short* __restrict__ hout)
{
  const int n = blockIdx.x * 4 + (threadIdx.x >> 6);
  if (n >= NN) return;
  const int lane = threadIdx.x & 63;
  const int d0 = lane * 2;
  const size_t base = (size_t)n * 128 + d0;

  const unsigned int qp = *(const unsigned int*)(q + base);
  const float q0 = bf2f(qp & 0xffff), q1 = bf2f(qp >> 16);

  float acc0 = 0.f, acc1 = 0.f, den = 0.f;
  const int s = rowstart[n], eend = rowstart[n + 1];
  const float scale = 0.17677669529663687f;   // 1/sqrt(32)

  int pos = s;
  for (; pos + 1 < eend; pos += 2) {
    const int2 rA = rec[pos], rB = rec[pos + 1];
    const unsigned int kpA = *(const unsigned int*)(k + (size_t)rA.x * 128 + d0);
    const unsigned int epA = *(const unsigned int*)(e + (size_t)rA.y * 128 + d0);
    const unsigned int vpA = *(const unsigned int*)(v + (size_t)rA.x * 128 + d0);
    const unsigned int kpB = *(const unsigned int*)(k + (size_t)rB.x * 128 + d0);
    const unsigned int epB = *(const unsigned int*)(e + (size_t)rB.y * 128 + d0);
    const unsigned int vpB = *(const unsigned int*)(v + (size_t)rB.x * 128 + d0);

    const float eA0 = bf2f(epA & 0xffff), eA1 = bf2f(epA >> 16);
    const float eB0 = bf2f(epB & 0xffff), eB1 = bf2f(epB >> 16);
    float dotA = q0 * (bf2f(kpA & 0xffff) + eA0) + q1 * (bf2f(kpA >> 16) + eA1);
    float dotB = q0 * (bf2f(kpB & 0xffff) + eB0) + q1 * (bf2f(kpB >> 16) + eB1);
    dotA += __shfl_xor(dotA, 1, 64); dotB += __shfl_xor(dotB, 1, 64);
    dotA += __shfl_xor(dotA, 2, 64); dotB += __shfl_xor(dotB, 2, 64);
    dotA += __shfl_xor(dotA, 4, 64); dotB += __shfl_xor(dotB, 4, 64);
    dotA += __shfl_xor(dotA, 8, 64); dotB += __shfl_xor(dotB, 8, 64);
    const float pA = expf(dotA * scale);
    const float pB = expf(dotB * scale);
    acc0 += pA * (bf2f(vpA & 0xffff) + eA0) + pB * (bf2f(vpB & 0xffff) + eB0);
    acc1 += pA * (bf2f(vpA >> 16) + eA1) + pB * (bf2f(vpB >> 16) + eB1);
    den  += pA + pB;
  }
  if (pos < eend) {
    const int2 rA = rec[pos];
    const unsigned int kpA = *(const unsigned int*)(k + (size_t)rA.x * 128 + d0);
    const unsigned int epA = *(const unsigned int*)(e + (size_t)rA.y * 128 + d0);
    const unsigned int vpA = *(const unsigned int*)(v + (size_t)rA.x * 128 + d0);
    const float eA0 = bf2f(epA & 0xffff), eA1 = bf2f(epA >> 16);
    float dotA = q0 * (bf2f(kpA & 0xffff) + eA0) + q1 * (bf2f(kpA >> 16) + eA1);
    dotA += __shfl_xor(dotA, 1, 64);
    dotA += __shfl_xor(dotA, 2, 64);
    dotA += __shfl_xor(dotA, 4, 64);
    dotA += __shfl_xor(dotA, 8, 64);
    const float pA = expf(dotA * scale);
    acc0 += pA * (bf2f(vpA & 0xffff) + eA0);
    acc1 += pA * (bf2f(vpA >> 16) + eA1);
    den  += pA;
  }

  const float dinv = 1.f / (den + 1e-16f);
  const float o0 = acc0 * dinv, o1 = acc1 * dinv;

  const float x0 = bf2f(xr[base]), x1 = bf2f(xr[base + 1]);
  float sb = o0 * Wb[d0] + o1 * Wb[d0 + 1]
           + x0 * Wb[128 + d0] + x1 * Wb[129 + d0]
           + (o0 - x0) * Wb[256 + d0] + (o1 - x1) * Wb[257 + d0];
  #pragma unroll
  for (int off = 32; off >= 1; off >>= 1) sb += __shfl_xor(sb, off, 64);
  const float beta = 1.f / (1.f + expf(-sb));

  float y0 = beta * x0 + (1.f - beta) * o0;
  float y1 = beta * x1 + (1.f - beta) * o1;
  y0 = 0.5f * y0 * (1.f + erff(y0 * 0.7071067811865475f));
  y1 = 0.5f * y1 * (1.f + erff(y1 * 0.7071067811865475f));

  float mu = y0 + y1;
  #pragma unroll
  for (int off = 32; off >= 1; off >>= 1) mu += __shfl_xor(mu, off, 64);
  mu *= (1.f / 128.f);
  float dv0 = y0 - mu, dv1 = y1 - mu;
  float var = dv0 * dv0 + dv1 * dv1;
  #pragma unroll
  for (int off = 32; off >= 1; off >>= 1) var += __shfl_xor(var, off, 64);
  var *= (1.f / 128.f);
  const float rs = rsqrtf(var + 1e-5f);

  float h0 = dv0 * rs * lng[d0] + lnb[d0];
  float h1 = dv1 * rs * lng[d0 + 1] + lnb[d0 + 1];
  if (prev) { h0 += bf2f(prev[base]); h1 += bf2f(prev[base + 1]); }
  unsigned int packed = (unsigned int)f2bf(h0) | ((unsigned int)f2bf(h1) << 16);
  *(unsigned int*)(hout + base) = packed;
}

// ================= gate =================
__global__ __launch_bounds__(256) void gate_kernel(
    const float* __restrict__ x, const float* __restrict__ Wg,
    const float* __restrict__ bg, float* __restrict__ g)
{
  const int row = blockIdx.x * 4 + (threadIdx.x >> 6);
  const int lane = threadIdx.x & 63;
  const size_t base = (size_t)row * 128 + lane * 2;
  float s = x[base] * Wg[lane * 2] + x[base + 1] * Wg[lane * 2 + 1];
  #pragma unroll
  for (int off = 32; off >= 1; off >>= 1) s += __shfl_xor(s, off, 64);
  g[row] = 1.f / (1.f + expf(-(s + bg[0])));
}

extern "C" void kernel_launch(void* const* d_in, const int* in_sizes, int n_in,
                              void* d_out, int out_size, void* d_ws, size_t ws_size,
                              hipStream_t stream)
{
  const float* x  = (const float*)d_in[0];
  const int*   ei = (const int*)d_in[1];
  const float* ea = (const float*)d_in[2];
  const float* Wq = (const float*)d_in[3];
  const float* bq = (const float*)d_in[4];
  const float* Wk = (const float*)d_in[5];
  const float* bk = (const float*)d_in[6];
  const float* Wv = (const float*)d_in[7];
  const float* bv = (const float*)d_in[8];
  const float* We = (const float*)d_in[9];
  const float* Ws = (const float*)d_in[10];
  const float* bs = (const float*)d_in[11];
  const float* Wb = (const float*)d_in[12];
  const float* lng= (const float*)d_in[13];
  const float* lnb= (const float*)d_in[14];
  const float* Wo = (const float*)d_in[15];
  const float* bo = (const float*)d_in[16];
  const float* Wg = (const float*)d_in[17];
  const float* bg = (const float*)d_in[18];
  float* outp = (float*)d_out;

  char* p = (char*)d_ws;
  auto take = [&](size_t b) -> char* { char* r = p; p += (b + 255) & ~(size_t)255; return r; };
  unsigned short* wT = (unsigned short*)take((size_t)11 * 16384 * 2);
  unsigned short* q  = (unsigned short*)take((size_t)NN * 128 * 2);
  unsigned short* k  = (unsigned short*)take((size_t)NN * 128 * 2);
  unsigned short* v  = (unsigned short*)take((size_t)NN * 128 * 2);
  unsigned short* xr = (unsigned short*)take((size_t)NN * 128 * 2);
  unsigned short* h1 = (unsigned short*)take((size_t)NN * 128 * 2);
  unsigned short* hs = (unsigned short*)take((size_t)NN * 128 * 2);
  float* gbuf = (float*)take((size_t)NN * 4);
  int* deg      = (int*)take((size_t)NN * 4);
  int* rowstart = (int*)take((size_t)(NN + 1) * 4);
  int* cursor   = (int*)take((size_t)NN * 4);
  int* bsum     = (int*)take((size_t)128 * 4);
  int2* rec     = (int2*)take((size_t)NE * 8);
  unsigned short* e0 = (unsigned short*)take((size_t)NE * 128 * 2);
  size_t used = (size_t)(p - (char*)d_ws);
  const bool dual = (used + (size_t)NE * 128 * 2) <= ws_size;
  unsigned short* e1 = dual ? (unsigned short*)take((size_t)NE * 128 * 2) : e0;

  const int SCAN_BLOCKS = (NN + 1023) / 1024;   // 98
  const int NTILE_E  = (NE + 127) / 128;        // 6250   (gemm_lds: 128 rows/block)
  const int NTILE_N  = (NN + 127) / 128;        // 782    (gemm_lds: 128 rows/block)
  const int NTILE_N64 = (NN + 63) / 64;         // 1563   (final_rs: 64 rows/block)

  // ---- CSR build ----
  hipMemsetAsync(deg, 0, (size_t)NN * 4, stream);
  hist_k<<<(NE + 255) / 256, 256, 0, stream>>>(ei, deg);
  scan1<<<SCAN_BLOCKS, 256, 0, stream>>>(deg, bsum);
  scan2<<<1, 64, 0, stream>>>(bsum, SCAN_BLOCKS, rowstart);
  scan3<<<SCAN_BLOCKS, 256, 0, stream>>>(deg, bsum, rowstart, cursor);
  scatter_k<<<(NE + 255) / 256, 256, 0, stream>>>(ei, cursor, rec);

  // ---- weights + edge projection (coalesced, edge order) ----
  conv_w<<<704, 256, 0, stream>>>(Wq, Wk, Wv, Ws, We, Wo, wT);
  if (dual) {
    gemm_lds<0,0,2><<<NTILE_E, 256, 0, stream>>>(ea, wT, 8, 9, nullptr, nullptr, e0, e1, NE);
  } else {
    gemm_lds<0,0,1><<<NTILE_E, 256, 0, stream>>>(ea, wT, 8, 8, nullptr, nullptr, e0, e0, NE);
  }

  // ---- layer 1 ----
  gemm_lds<0,1,2><<<NTILE_N, 256, 0, stream>>>(x, wT, 0, 1, bq, bk, q, k, NN);
  gemm_lds<0,1,2><<<NTILE_N, 256, 0, stream>>>(x, wT, 2, 3, bv, bs, v, xr, NN);
  csr_attn<<<25000, 256, 0, stream>>>(rowstart, rec, e0, q, k, v, xr, Wb, lng, lnb, nullptr, h1);

  // ---- layer 2 ----
  if (!dual) gemm_lds<0,0,1><<<NTILE_E, 256, 0, stream>>>(ea, wT, 9, 9, nullptr, nullptr, e0, e0, NE);
  gemm_lds<1,1,2><<<NTILE_N, 256, 0, stream>>>(h1, wT, 4, 5, bq + 128, bk + 128, q, k, NN);
  gemm_lds<1,1,2><<<NTILE_N, 256, 0, stream>>>(h1, wT, 6, 7, bv + 128, bs + 128, v, xr, NN);
  csr_attn<<<25000, 256, 0, stream>>>(rowstart, rec, e1, q, k, v, xr, Wb + 384, lng + 128, lnb + 128, h1, hs);

  // ---- final ----
  gate_kernel<<<25000, 256, 0, stream>>>(x, Wg, bg, gbuf);
  final_rs<<<NTILE_N64, 256, 0, stream>>>(hs, wT + (size_t)10 * 16384, bo, x, gbuf, outp, NN);
}

// Round 10
// 763.629 us; speedup vs baseline: 1.4701x; 1.0319x over previous
//
#include <hip/hip_runtime.h>
#include <math.h>

#define NN 100000
#define NE 800000
// DIM=128, HEADS=4, CH=32

typedef __attribute__((ext_vector_type(8))) short short8;
typedef __attribute__((ext_vector_type(4))) float f32x4;

__device__ __forceinline__ float bf2f(unsigned short u) {
  union { float f; unsigned int i; } x; x.i = ((unsigned int)u) << 16; return x.f;
}
__device__ __forceinline__ unsigned short f2bf(float f) {
  union { float f; unsigned int i; } x; x.f = f;
  unsigned int r = x.i + 0x7fffu + ((x.i >> 16) & 1u);
  return (unsigned short)(r >> 16);
}

__device__ __forceinline__ short8 load8_f32_as_bf16(const float* p) {
  const float4 a = *(const float4*)p;
  const float4 b = *(const float4*)(p + 4);
  short8 r;
  r[0] = (short)f2bf(a.x); r[1] = (short)f2bf(a.y); r[2] = (short)f2bf(a.z); r[3] = (short)f2bf(a.w);
  r[4] = (short)f2bf(b.x); r[5] = (short)f2bf(b.y); r[6] = (short)f2bf(b.z); r[7] = (short)f2bf(b.w);
  return r;
}

// ================= CSR build =================
__global__ __launch_bounds__(256) void hist_k(const int* __restrict__ ei, int* __restrict__ deg) {
  int t = blockIdx.x * 256 + threadIdx.x;
  if (t < NE) atomicAdd(&deg[ei[NE + t]], 1);
}

__global__ __launch_bounds__(256) void scan1(const int* __restrict__ deg, int* __restrict__ bsum) {
  __shared__ int sd[256];
  const int b = blockIdx.x, t = threadIdx.x, base = b * 1024;
  int s = 0;
  #pragma unroll
  for (int i = 0; i < 4; i++) { int idx = base + t * 4 + i; if (idx < NN) s += deg[idx]; }
  sd[t] = s; __syncthreads();
  for (int off = 128; off >= 1; off >>= 1) { if (t < off) sd[t] += sd[t + off]; __syncthreads(); }
  if (t == 0) bsum[b] = sd[0];
}

__global__ void scan2(int* __restrict__ bsum, int nb, int* __restrict__ rowstart) {
  if (threadIdx.x == 0 && blockIdx.x == 0) {
    int run = 0;
    for (int i = 0; i < nb; i++) { int v = bsum[i]; bsum[i] = run; run += v; }
    rowstart[NN] = run;
  }
}

__global__ __launch_bounds__(256) void scan3(const int* __restrict__ deg, const int* __restrict__ bsum,
                                             int* __restrict__ rowstart, int* __restrict__ cursor) {
  __shared__ int sd[256];
  const int b = blockIdx.x, t = threadIdx.x, base = b * 1024;
  int vals[4]; int s = 0;
  #pragma unroll
  for (int i = 0; i < 4; i++) { int idx = base + t * 4 + i; vals[i] = (idx < NN) ? deg[idx] : 0; s += vals[i]; }
  sd[t] = s; __syncthreads();
  int excl = 0;
  for (int i = 0; i < t; i++) excl += sd[i];
  int run = bsum[b] + excl;
  #pragma unroll
  for (int i = 0; i < 4; i++) {
    int idx = base + t * 4 + i;
    if (idx < NN) { rowstart[idx] = run; cursor[idx] = run; run += vals[i]; }
  }
}

__global__ __launch_bounds__(256) void scatter_k(const int* __restrict__ ei, int* __restrict__ cursor,
                                                 int2* __restrict__ rec) {
  int t = blockIdx.x * 256 + threadIdx.x;
  if (t >= NE) return;
  int dst = ei[NE + t];
  int pos = atomicAdd(&cursor[dst], 1);
  rec[pos] = make_int2(ei[t], t);   // {src, edge_id}
}

// ================= weight prep =================
// slots: 0..3 = Wq0,Wk0,Wv0,Ws0 ; 4..7 = Wq1,Wk1,Wv1,Ws1 ; 8,9 = We0,We1 ; 10 = Wo
__global__ __launch_bounds__(256) void conv_w(
    const float* __restrict__ Wq, const float* __restrict__ Wk, const float* __restrict__ Wv,
    const float* __restrict__ Ws, const float* __restrict__ We, const float* __restrict__ Wo,
    unsigned short* __restrict__ wT)
{
  int idx = blockIdx.x * 256 + threadIdx.x;   // 11*16384 total
  int m = idx >> 14;
  int r = idx & 16383;
  int n = r >> 7, kk = r & 127;
  const float* src;
  switch (m) {
    case 0: src = Wq; break;
    case 1: src = Wk; break;
    case 2: src = Wv; break;
    case 3: src = Ws; break;
    case 4: src = Wq + 16384; break;
    case 5: src = Wk + 16384; break;
    case 6: src = Wv + 16384; break;
    case 7: src = Ws + 16384; break;
    case 8: src = We; break;
    case 9: src = We + 16384; break;
    default: src = Wo; break;
  }
  wT[idx] = f2bf(src[(size_t)kk * 128 + n]);
}

// ================= LDS-staged GEMM, register weights, swapped-operand MFMA =================
// C = A[M,128] @ wT[slot] (+bias), bf16 out.
// Block = 4 waves, 128-row tile. A staged cooperatively into LDS; per-rg wave-local
// LDS transpose of output fragments -> one 16B full-line store per lane per mat.
template<int ABF16, int HASBIAS, int NMAT>
__global__ __launch_bounds__(256, 2) void gemm_lds(
    const void* __restrict__ Ap, const unsigned short* __restrict__ wT, int s0, int s1,
    const float* __restrict__ bias0, const float* __restrict__ bias1,
    unsigned short* __restrict__ o0, unsigned short* __restrict__ o1, int M)
{
  __shared__ __align__(16) unsigned short As[128 * 136];    // 34.8 KB
  __shared__ __align__(16) unsigned short Os[4 * 16 * 36];  // 4.6 KB, per-wave strips
  const int wave = threadIdx.x >> 6, lane = threadIdx.x & 63;
  const int l15 = lane & 15, g = lane >> 4;
  const int colf = wave * 32;
  const int rb = blockIdx.x * 128;
  unsigned short* os = Os + wave * (16 * 36);

  // --- preload weight fragments into registers (once) ---
  short8 wf[NMAT][2][4];
  const int slots[2] = { s0, s1 };
  #pragma unroll
  for (int m = 0; m < NMAT; ++m) {
    const unsigned short* wp = wT + (size_t)slots[m] * 16384;
    #pragma unroll
    for (int cb = 0; cb < 2; ++cb) {
      const int col = colf + cb * 16 + l15;
      #pragma unroll
      for (int kt = 0; kt < 4; ++kt)
        wf[m][cb][kt] = *(const short8*)(wp + (size_t)col * 128 + kt * 32 + g * 8);
    }
  }
  float bia[NMAT][2][4];
  if (HASBIAS) {
    const float* bp[2] = { bias0, bias1 };
    #pragma unroll
    for (int m = 0; m < NMAT; ++m)
      #pragma unroll
      for (int cb = 0; cb < 2; ++cb)
        #pragma unroll
        for (int j = 0; j < 4; ++j)
          bia[m][cb][j] = bp[m][colf + cb * 16 + g * 4 + j];
  }

  // --- cooperative stage: thread t -> row t&127, half t>>7 (64 cols) ---
  {
    const int r = threadIdx.x & 127;
    const int hf = threadIdx.x >> 7;
    const int gr = rb + r;
    const int ar = (gr < M) ? gr : (M - 1);
    unsigned short* dst = As + r * 136 + hf * 64;
    if (ABF16) {
      const unsigned short* srcp = (const unsigned short*)Ap + (size_t)ar * 128 + hf * 64;
      #pragma unroll
      for (int i = 0; i < 8; ++i)
        *(short8*)(dst + i * 8) = *(const short8*)(srcp + i * 8);
    } else {
      const float* srcp = (const float*)Ap + (size_t)ar * 128 + hf * 64;
      #pragma unroll
      for (int i = 0; i < 8; ++i)
        *(short8*)(dst + i * 8) = load8_f32_as_bf16(srcp + i * 8);
    }
  }
  __syncthreads();

  const int srow = rb + l15;   // store row for this lane within a rg

  #pragma unroll
  for (int rg = 0; rg < 8; ++rg) {
    const int row = rg * 16 + l15;
    short8 a[4];
    #pragma unroll
    for (int kt = 0; kt < 4; ++kt)
      a[kt] = *(const short8*)(As + row * 136 + kt * 32 + g * 8);

    #pragma unroll
    for (int m = 0; m < NMAT; ++m) {
      // compute both column-blocks for this mat
      #pragma unroll
      for (int cb = 0; cb < 2; ++cb) {
        f32x4 acc; acc[0] = 0.f; acc[1] = 0.f; acc[2] = 0.f; acc[3] = 0.f;
        #pragma unroll
        for (int kt = 0; kt < 4; ++kt)
          acc = __builtin_amdgcn_mfma_f32_16x16x32_bf16(wf[m][cb][kt], a[kt], acc, 0, 0, 0);
        float f0 = acc[0], f1 = acc[1], f2 = acc[2], f3 = acc[3];
        if (HASBIAS) { f0 += bia[m][cb][0]; f1 += bia[m][cb][1]; f2 += bia[m][cb][2]; f3 += bia[m][cb][3]; }
        uint2 pk;
        pk.x = (unsigned int)f2bf(f0) | ((unsigned int)f2bf(f1) << 16);
        pk.y = (unsigned int)f2bf(f2) | ((unsigned int)f2bf(f3) << 16);
        // frag -> wave-local LDS strip: row l15, col cb*16 + g*4
        *(uint2*)(os + l15 * 36 + cb * 16 + g * 4) = pk;
      }
      // wave-internal transpose read: lane -> row lane&15, 8-col chunk g
      short8 vv = *(const short8*)(os + l15 * 36 + g * 8);
      const int r = srow + rg * 16;
      if (r < M) {
        unsigned short* op = (m == 0) ? o0 : o1;
        *(short8*)(op + (size_t)r * 128 + colf + g * 8) = vv;
      }
    }
  }
}

// ================= final GEMM + gate epilogue (f32 out), 64 rows/block =================
__global__ __launch_bounds__(256, 3) void final_rs(
    const unsigned short* __restrict__ A, const unsigned short* __restrict__ wp,
    const float* __restrict__ bo, const float* __restrict__ xin,
    const float* __restrict__ gate, float* __restrict__ out, int M)
{
  const int wave = threadIdx.x >> 6, lane = threadIdx.x & 63;
  const int l15 = lane & 15, g = lane >> 4;
  const int colf = wave * 32;
  const int rb = blockIdx.x * 64;

  short8 wf[2][4];
  #pragma unroll
  for (int cb = 0; cb < 2; ++cb) {
    const int col = colf + cb * 16 + l15;
    #pragma unroll
    for (int kt = 0; kt < 4; ++kt)
      wf[cb][kt] = *(const short8*)(wp + (size_t)col * 128 + kt * 32 + g * 8);
  }
  float bia[2][4];
  #pragma unroll
  for (int cb = 0; cb < 2; ++cb)
    #pragma unroll
    for (int j = 0; j < 4; ++j)
      bia[cb][j] = bo[colf + cb * 16 + g * 4 + j];

  #pragma unroll
  for (int rg = 0; rg < 4; ++rg) {
    const int r = rb + rg * 16 + l15;
    const int ar = (r < M) ? r : (M - 1);
    short8 a[4];
    #pragma unroll
    for (int kt = 0; kt < 4; ++kt)
      a[kt] = *(const short8*)(A + (size_t)ar * 128 + kt * 32 + g * 8);

    f32x4 accs[2];
    #pragma unroll
    for (int cb = 0; cb < 2; ++cb) {
      f32x4 acc; acc[0] = 0.f; acc[1] = 0.f; acc[2] = 0.f; acc[3] = 0.f;
      #pragma unroll
      for (int kt = 0; kt < 4; ++kt)
        acc = __builtin_amdgcn_mfma_f32_16x16x32_bf16(wf[cb][kt], a[kt], acc, 0, 0, 0);
      accs[cb] = acc;
    }

    if (r < M) {
      const float gr = gate[r];
      #pragma unroll
      for (int cb = 0; cb < 2; ++cb) {
        const int c0 = colf + cb * 16 + g * 4;
        const float4 xv = *(const float4*)(xin + (size_t)r * 128 + c0);
        float4 res;
        res.x = gr * xv.x + (1.f - gr) * (accs[cb][0] + bia[cb][0]);
        res.y = gr * xv.y + (1.f - gr) * (accs[cb][1] + bia[cb][1]);
        res.z = gr * xv.z + (1.f - gr) * (accs[cb][2] + bia[cb][2]);
        res.w = gr * xv.w + (1.f - gr) * (accs[cb][3] + bia[cb][3]);
        *(float4*)(out + (size_t)r * 128 + c0) = res;
      }
    }
  }
}

// ================= fused CSR attention + node epilogue =================
// e stays in edge order; rec[pos] = {src, edge_id} sorted by dst.
__global__ __launch_bounds__(256) void csr_attn(
    const int* __restrict__ rowstart, const int2* __restrict__ rec,
    const unsigned short* __restrict__ e,
    const unsigned short* __restrict__ q, const unsigned short* __restrict__ k,
    const unsigned short* __restrict__ v, const unsigned short* __restrict__ xr,
    const float* __restrict__ Wb, const float* __restrict__ lng, const float* __restrict__ lnb,
    const unsigned short* __restrict__ prev, unsigned short* __restrict__ hout)
{
  const int n = blockIdx.x * 4 + (threadIdx.x >> 6);
  if (n >= NN) return;
  const int lane = threadIdx.x & 63;
  const int d0 = lane * 2;
  const size_t base = (size_t)n * 128 + d0;

  const unsigned int qp = *(const unsigned int*)(q + base);
  const float q0 = bf2f(qp & 0xffff), q1 = bf2f(qp >> 16);

  float acc0 = 0.f, acc1 = 0.f, den = 0.f;
  const int s = rowstart[n], eend = rowstart[n + 1];
  const float scale = 0.17677669529663687f;   // 1/sqrt(32)

  int pos = s;
  for (; pos + 1 < eend; pos += 2) {
    const int2 rA = rec[pos], rB = rec[pos + 1];
    const unsigned int kpA = *(const unsigned int*)(k + (size_t)rA.x * 128 + d0);
    const unsigned int epA = *(const unsigned int*)(e + (size_t)rA.y * 128 + d0);
    const unsigned int vpA = *(const unsigned int*)(v + (size_t)rA.x * 128 + d0);
    const unsigned int kpB = *(const unsigned int*)(k + (size_t)rB.x * 128 + d0);
    const unsigned int epB = *(const unsigned int*)(e + (size_t)rB.y * 128 + d0);
    const unsigned int vpB = *(const unsigned int*)(v + (size_t)rB.x * 128 + d0);

    const float eA0 = bf2f(epA & 0xffff), eA1 = bf2f(epA >> 16);
    const float eB0 = bf2f(epB & 0xffff), eB1 = bf2f(epB >> 16);
    float dotA = q0 * (bf2f(kpA & 0xffff) + eA0) + q1 * (bf2f(kpA >> 16) + eA1);
    float dotB = q0 * (bf2f(kpB & 0xffff) + eB0) + q1 * (bf2f(kpB >> 16) + eB1);
    dotA += __shfl_xor(dotA, 1, 64); dotB += __shfl_xor(dotB, 1, 64);
    dotA += __shfl_xor(dotA, 2, 64); dotB += __shfl_xor(dotB, 2, 64);
    dotA += __shfl_xor(dotA, 4, 64); dotB += __shfl_xor(dotB, 4, 64);
    dotA += __shfl_xor(dotA, 8, 64); dotB += __shfl_xor(dotB, 8, 64);
    const float pA = expf(dotA * scale);
    const float pB = expf(dotB * scale);
    acc0 += pA * (bf2f(vpA & 0xffff) + eA0) + pB * (bf2f(vpB & 0xffff) + eB0);
    acc1 += pA * (bf2f(vpA >> 16) + eA1) + pB * (bf2f(vpB >> 16) + eB1);
    den  += pA + pB;
  }
  if (pos < eend) {
    const int2 rA = rec[pos];
    const unsigned int kpA = *(const unsigned int*)(k + (size_t)rA.x * 128 + d0);
    const unsigned int epA = *(const unsigned int*)(e + (size_t)rA.y * 128 + d0);
    const unsigned int vpA = *(const unsigned int*)(v + (size_t)rA.x * 128 + d0);
    const float eA0 = bf2f(epA & 0xffff), eA1 = bf2f(epA >> 16);
    float dotA = q0 * (bf2f(kpA & 0xffff) + eA0) + q1 * (bf2f(kpA >> 16) + eA1);
    dotA += __shfl_xor(dotA, 1, 64);
    dotA += __shfl_xor(dotA, 2, 64);
    dotA += __shfl_xor(dotA, 4, 64);
    dotA += __shfl_xor(dotA, 8, 64);
    const float pA = expf(dotA * scale);
    acc0 += pA * (bf2f(vpA & 0xffff) + eA0);
    acc1 += pA * (bf2f(vpA >> 16) + eA1);
    den  += pA;
  }

  const float dinv = 1.f / (den + 1e-16f);
  const float o0 = acc0 * dinv, o1 = acc1 * dinv;

  const float x0 = bf2f(xr[base]), x1 = bf2f(xr[base + 1]);
  float sb = o0 * Wb[d0] + o1 * Wb[d0 + 1]
           + x0 * Wb[128 + d0] + x1 * Wb[129 + d0]
           + (o0 - x0) * Wb[256 + d0] + (o1 - x1) * Wb[257 + d0];
  #pragma unroll
  for (int off = 32; off >= 1; off >>= 1) sb += __shfl_xor(sb, off, 64);
  const float beta = 1.f / (1.f + expf(-sb));

  float y0 = beta * x0 + (1.f - beta) * o0;
  float y1 = beta * x1 + (1.f - beta) * o1;
  y0 = 0.5f * y0 * (1.f + erff(y0 * 0.7071067811865475f));
  y1 = 0.5f * y1 * (1.f + erff(y1 * 0.7071067811865475f));

  float mu = y0 + y1;
  #pragma unroll
  for (int off = 32; off >= 1; off >>= 1) mu += __shfl_xor(mu, off, 64);
  mu *= (1.f / 128.f);
  float dv0 = y0 - mu, dv1 = y1 - mu;
  float var = dv0 * dv0 + dv1 * dv1;
  #pragma unroll
  for (int off = 32; off >= 1; off >>= 1) var += __shfl_xor(var, off, 64);
  var *= (1.f / 128.f);
  const float rs = rsqrtf(var + 1e-5f);

  float h0 = dv0 * rs * lng[d0] + lnb[d0];
  float h1 = dv1 * rs * lng[d0 + 1] + lnb[d0 + 1];
  if (prev) { h0 += bf2f(prev[base]); h1 += bf2f(prev[base + 1]); }
  unsigned int packed = (unsigned int)f2bf(h0) | ((unsigned int)f2bf(h1) << 16);
  *(unsigned int*)(hout + base) = packed;
}

// ================= gate =================
__global__ __launch_bounds__(256) void gate_kernel(
    const float* __restrict__ x, const float* __restrict__ Wg,
    const float* __restrict__ bg, float* __restrict__ g)
{
  const int row = blockIdx.x * 4 + (threadIdx.x >> 6);
  const int lane = threadIdx.x & 63;
  const size_t base = (size_t)row * 128 + lane * 2;
  float s = x[base] * Wg[lane * 2] + x[base + 1] * Wg[lane * 2 + 1];
  #pragma unroll
  for (int off = 32; off >= 1; off >>= 1) s += __shfl_xor(s, off, 64);
  g[row] = 1.f / (1.f + expf(-(s + bg[0])));
}

extern "C" void kernel_launch(void* const* d_in, const int* in_sizes, int n_in,
                              void* d_out, int out_size, void* d_ws, size_t ws_size,
                              hipStream_t stream)
{
  const float* x  = (const float*)d_in[0];
  const int*   ei = (const int*)d_in[1];
  const float* ea = (const float*)d_in[2];
  const float* Wq = (const float*)d_in[3];
  const float* bq = (const float*)d_in[4];
  const float* Wk = (const float*)d_in[5];
  const float* bk = (const float*)d_in[6];
  const float* Wv = (const float*)d_in[7];
  const float* bv = (const float*)d_in[8];
  const float* We = (const float*)d_in[9];
  const float* Ws = (const float*)d_in[10];
  const float* bs = (const float*)d_in[11];
  const float* Wb = (const float*)d_in[12];
  const float* lng= (const float*)d_in[13];
  const float* lnb= (const float*)d_in[14];
  const float* Wo = (const float*)d_in[15];
  const float* bo = (const float*)d_in[16];
  const float* Wg = (const float*)d_in[17];
  const float* bg = (const float*)d_in[18];
  float* outp = (float*)d_out;

  char* p = (char*)d_ws;
  auto take = [&](size_t b) -> char* { char* r = p; p += (b + 255) & ~(size_t)255; return r; };
  unsigned short* wT = (unsigned short*)take((size_t)11 * 16384 * 2);
  unsigned short* q  = (unsigned short*)take((size_t)NN * 128 * 2);
  unsigned short* k  = (unsigned short*)take((size_t)NN * 128 * 2);
  unsigned short* v  = (unsigned short*)take((size_t)NN * 128 * 2);
  unsigned short* xr = (unsigned short*)take((size_t)NN * 128 * 2);
  unsigned short* h1 = (unsigned short*)take((size_t)NN * 128 * 2);
  unsigned short* hs = (unsigned short*)take((size_t)NN * 128 * 2);
  float* gbuf = (float*)take((size_t)NN * 4);
  int* deg      = (int*)take((size_t)NN * 4);
  int* rowstart = (int*)take((size_t)(NN + 1) * 4);
  int* cursor   = (int*)take((size_t)NN * 4);
  int* bsum     = (int*)take((size_t)128 * 4);
  int2* rec     = (int2*)take((size_t)NE * 8);
  unsigned short* e0 = (unsigned short*)take((size_t)NE * 128 * 2);
  size_t used = (size_t)(p - (char*)d_ws);
  const bool dual = (used + (size_t)NE * 128 * 2) <= ws_size;
  unsigned short* e1 = dual ? (unsigned short*)take((size_t)NE * 128 * 2) : e0;

  const int SCAN_BLOCKS = (NN + 1023) / 1024;   // 98
  const int NTILE_E  = (NE + 127) / 128;        // 6250   (gemm_lds: 128 rows/block)
  const int NTILE_N  = (NN + 127) / 128;        // 782    (gemm_lds: 128 rows/block)
  const int NTILE_N64 = (NN + 63) / 64;         // 1563   (final_rs: 64 rows/block)

  // ---- CSR build ----
  hipMemsetAsync(deg, 0, (size_t)NN * 4, stream);
  hist_k<<<(NE + 255) / 256, 256, 0, stream>>>(ei, deg);
  scan1<<<SCAN_BLOCKS, 256, 0, stream>>>(deg, bsum);
  scan2<<<1, 64, 0, stream>>>(bsum, SCAN_BLOCKS, rowstart);
  scan3<<<SCAN_BLOCKS, 256, 0, stream>>>(deg, bsum, rowstart, cursor);
  scatter_k<<<(NE + 255) / 256, 256, 0, stream>>>(ei, cursor, rec);

  // ---- weights + edge projection (coalesced, edge order) ----
  conv_w<<<704, 256, 0, stream>>>(Wq, Wk, Wv, Ws, We, Wo, wT);
  if (dual) {
    gemm_lds<0,0,2><<<NTILE_E, 256, 0, stream>>>(ea, wT, 8, 9, nullptr, nullptr, e0, e1, NE);
  } else {
    gemm_lds<0,0,1><<<NTILE_E, 256, 0, stream>>>(ea, wT, 8, 8, nullptr, nullptr, e0, e0, NE);
  }

  // ---- layer 1 ----
  gemm_lds<0,1,2><<<NTILE_N, 256, 0, stream>>>(x, wT, 0, 1, bq, bk, q, k, NN);
  gemm_lds<0,1,2><<<NTILE_N, 256, 0, stream>>>(x, wT, 2, 3, bv, bs, v, xr, NN);
  csr_attn<<<25000, 256, 0, stream>>>(rowstart, rec, e0, q, k, v, xr, Wb, lng, lnb, nullptr, h1);

  // ---- layer 2 ----
  if (!dual) gemm_lds<0,0,1><<<NTILE_E, 256, 0, stream>>>(ea, wT, 9, 9, nullptr, nullptr, e0, e0, NE);
  gemm_lds<1,1,2><<<NTILE_N, 256, 0, stream>>>(h1, wT, 4, 5, bq + 128, bk + 128, q, k, NN);
  gemm_lds<1,1,2><<<NTILE_N, 256, 0, stream>>>(h1, wT, 6, 7, bv + 128, bs + 128, v, xr, NN);
  csr_attn<<<25000, 256, 0, stream>>>(rowstart, rec, e1, q, k, v, xr, Wb + 384, lng + 128, lnb + 128, h1, hs);

  // ---- final ----
  gate_kernel<<<25000, 256, 0, stream>>>(x, Wg, bg, gbuf);
  final_rs<<<NTILE_N64, 256, 0, stream>>>(hs, wT + (size_t)10 * 16384, bo, x, gbuf, outp, NN);
}

// Round 11
// 730.475 us; speedup vs baseline: 1.5368x; 1.0454x over previous
//
#include <hip/hip_runtime.h>
#include <math.h>

#define NN 100000
#define NE 800000
// DIM=128, HEADS=4, CH=32

typedef __attribute__((ext_vector_type(8))) short short8;
typedef __attribute__((ext_vector_type(4))) float f32x4;

__device__ __forceinline__ float bf2f(unsigned short u) {
  union { float f; unsigned int i; } x; x.i = ((unsigned int)u) << 16; return x.f;
}
__device__ __forceinline__ unsigned short f2bf(float f) {
  union { float f; unsigned int i; } x; x.f = f;
  unsigned int r = x.i + 0x7fffu + ((x.i >> 16) & 1u);
  return (unsigned short)(r >> 16);
}

__device__ __forceinline__ short8 load8_f32_as_bf16(const float* p) {
  const float4 a = *(const float4*)p;
  const float4 b = *(const float4*)(p + 4);
  short8 r;
  r[0] = (short)f2bf(a.x); r[1] = (short)f2bf(a.y); r[2] = (short)f2bf(a.z); r[3] = (short)f2bf(a.w);
  r[4] = (short)f2bf(b.x); r[5] = (short)f2bf(b.y); r[6] = (short)f2bf(b.z); r[7] = (short)f2bf(b.w);
  return r;
}

// ================= CSR build =================
__global__ __launch_bounds__(256) void hist_k(const int* __restrict__ ei, int* __restrict__ deg) {
  int t = blockIdx.x * 256 + threadIdx.x;
  if (t < NE) atomicAdd(&deg[ei[NE + t]], 1);
}

__global__ __launch_bounds__(256) void scan1(const int* __restrict__ deg, int* __restrict__ bsum) {
  __shared__ int sd[256];
  const int b = blockIdx.x, t = threadIdx.x, base = b * 1024;
  int s = 0;
  #pragma unroll
  for (int i = 0; i < 4; i++) { int idx = base + t * 4 + i; if (idx < NN) s += deg[idx]; }
  sd[t] = s; __syncthreads();
  for (int off = 128; off >= 1; off >>= 1) { if (t < off) sd[t] += sd[t + off]; __syncthreads(); }
  if (t == 0) bsum[b] = sd[0];
}

__global__ void scan2(int* __restrict__ bsum, int nb, int* __restrict__ rowstart) {
  if (threadIdx.x == 0 && blockIdx.x == 0) {
    int run = 0;
    for (int i = 0; i < nb; i++) { int v = bsum[i]; bsum[i] = run; run += v; }
    rowstart[NN] = run;
  }
}

__global__ __launch_bounds__(256) void scan3(const int* __restrict__ deg, const int* __restrict__ bsum,
                                             int* __restrict__ rowstart, int* __restrict__ cursor) {
  __shared__ int sd[256];
  const int b = blockIdx.x, t = threadIdx.x, base = b * 1024;
  int vals[4]; int s = 0;
  #pragma unroll
  for (int i = 0; i < 4; i++) { int idx = base + t * 4 + i; vals[i] = (idx < NN) ? deg[idx] : 0; s += vals[i]; }
  sd[t] = s; __syncthreads();
  int excl = 0;
  for (int i = 0; i < t; i++) excl += sd[i];
  int run = bsum[b] + excl;
  #pragma unroll
  for (int i = 0; i < 4; i++) {
    int idx = base + t * 4 + i;
    if (idx < NN) { rowstart[idx] = run; cursor[idx] = run; run += vals[i]; }
  }
}

__global__ __launch_bounds__(256) void scatter_k(const int* __restrict__ ei, int* __restrict__ cursor,
                                                 int2* __restrict__ rec) {
  int t = blockIdx.x * 256 + threadIdx.x;
  if (t >= NE) return;
  int dst = ei[NE + t];
  int pos = atomicAdd(&cursor[dst], 1);
  rec[pos] = make_int2(ei[t], t);   // {src, edge_id}
}

// ================= weight prep =================
// slots: 0..3 = Wq0,Wk0,Wv0,Ws0 ; 4..7 = Wq1,Wk1,Wv1,Ws1 ; 8,9 = We0,We1 ; 10 = Wo
__global__ __launch_bounds__(256) void conv_w(
    const float* __restrict__ Wq, const float* __restrict__ Wk, const float* __restrict__ Wv,
    const float* __restrict__ Ws, const float* __restrict__ We, const float* __restrict__ Wo,
    unsigned short* __restrict__ wT)
{
  int idx = blockIdx.x * 256 + threadIdx.x;   // 11*16384 total
  int m = idx >> 14;
  int r = idx & 16383;
  int n = r >> 7, kk = r & 127;
  const float* src;
  switch (m) {
    case 0: src = Wq; break;
    case 1: src = Wk; break;
    case 2: src = Wv; break;
    case 3: src = Ws; break;
    case 4: src = Wq + 16384; break;
    case 5: src = Wk + 16384; break;
    case 6: src = Wv + 16384; break;
    case 7: src = Ws + 16384; break;
    case 8: src = We; break;
    case 9: src = We + 16384; break;
    default: src = Wo; break;
  }
  wT[idx] = f2bf(src[(size_t)kk * 128 + n]);
}

// ================= LDS-staged GEMM, register weights, swapped-operand MFMA =================
template<int ABF16, int HASBIAS, int NMAT>
__global__ __launch_bounds__(256, 2) void gemm_lds(
    const void* __restrict__ Ap, const unsigned short* __restrict__ wT, int s0, int s1,
    const float* __restrict__ bias0, const float* __restrict__ bias1,
    unsigned short* __restrict__ o0, unsigned short* __restrict__ o1, int M)
{
  __shared__ __align__(16) unsigned short As[128 * 136];    // 34.8 KB
  __shared__ __align__(16) unsigned short Os[4 * 16 * 36];  // 4.6 KB, per-wave strips
  const int wave = threadIdx.x >> 6, lane = threadIdx.x & 63;
  const int l15 = lane & 15, g = lane >> 4;
  const int colf = wave * 32;
  const int rb = blockIdx.x * 128;
  unsigned short* os = Os + wave * (16 * 36);

  short8 wf[NMAT][2][4];
  const int slots[2] = { s0, s1 };
  #pragma unroll
  for (int m = 0; m < NMAT; ++m) {
    const unsigned short* wp = wT + (size_t)slots[m] * 16384;
    #pragma unroll
    for (int cb = 0; cb < 2; ++cb) {
      const int col = colf + cb * 16 + l15;
      #pragma unroll
      for (int kt = 0; kt < 4; ++kt)
        wf[m][cb][kt] = *(const short8*)(wp + (size_t)col * 128 + kt * 32 + g * 8);
    }
  }
  float bia[NMAT][2][4];
  if (HASBIAS) {
    const float* bp[2] = { bias0, bias1 };
    #pragma unroll
    for (int m = 0; m < NMAT; ++m)
      #pragma unroll
      for (int cb = 0; cb < 2; ++cb)
        #pragma unroll
        for (int j = 0; j < 4; ++j)
          bia[m][cb][j] = bp[m][colf + cb * 16 + g * 4 + j];
  }

  // --- cooperative stage: thread t -> row t&127, half t>>7 (64 cols) ---
  {
    const int r = threadIdx.x & 127;
    const int hf = threadIdx.x >> 7;
    const int gr = rb + r;
    const int ar = (gr < M) ? gr : (M - 1);
    unsigned short* dst = As + r * 136 + hf * 64;
    if (ABF16) {
      const unsigned short* srcp = (const unsigned short*)Ap + (size_t)ar * 128 + hf * 64;
      #pragma unroll
      for (int i = 0; i < 8; ++i)
        *(short8*)(dst + i * 8) = *(const short8*)(srcp + i * 8);
    } else {
      const float* srcp = (const float*)Ap + (size_t)ar * 128 + hf * 64;
      #pragma unroll
      for (int i = 0; i < 8; ++i)
        *(short8*)(dst + i * 8) = load8_f32_as_bf16(srcp + i * 8);
    }
  }
  __syncthreads();

  const int srow = rb + l15;

  #pragma unroll
  for (int rg = 0; rg < 8; ++rg) {
    const int row = rg * 16 + l15;
    short8 a[4];
    #pragma unroll
    for (int kt = 0; kt < 4; ++kt)
      a[kt] = *(const short8*)(As + row * 136 + kt * 32 + g * 8);

    #pragma unroll
    for (int m = 0; m < NMAT; ++m) {
      #pragma unroll
      for (int cb = 0; cb < 2; ++cb) {
        f32x4 acc; acc[0] = 0.f; acc[1] = 0.f; acc[2] = 0.f; acc[3] = 0.f;
        #pragma unroll
        for (int kt = 0; kt < 4; ++kt)
          acc = __builtin_amdgcn_mfma_f32_16x16x32_bf16(wf[m][cb][kt], a[kt], acc, 0, 0, 0);
        float f0 = acc[0], f1 = acc[1], f2 = acc[2], f3 = acc[3];
        if (HASBIAS) { f0 += bia[m][cb][0]; f1 += bia[m][cb][1]; f2 += bia[m][cb][2]; f3 += bia[m][cb][3]; }
        uint2 pk;
        pk.x = (unsigned int)f2bf(f0) | ((unsigned int)f2bf(f1) << 16);
        pk.y = (unsigned int)f2bf(f2) | ((unsigned int)f2bf(f3) << 16);
        *(uint2*)(os + l15 * 36 + cb * 16 + g * 4) = pk;
      }
      short8 vv = *(const short8*)(os + l15 * 36 + g * 8);
      const int r = srow + rg * 16;
      if (r < M) {
        unsigned short* op = (m == 0) ? o0 : o1;
        *(short8*)(op + (size_t)r * 128 + colf + g * 8) = vv;
      }
    }
  }
}

// ================= final GEMM + gate epilogue (f32 out), 64 rows/block =================
__global__ __launch_bounds__(256, 3) void final_rs(
    const unsigned short* __restrict__ A, const unsigned short* __restrict__ wp,
    const float* __restrict__ bo, const float* __restrict__ xin,
    const float* __restrict__ gate, float* __restrict__ out, int M)
{
  const int wave = threadIdx.x >> 6, lane = threadIdx.x & 63;
  const int l15 = lane & 15, g = lane >> 4;
  const int colf = wave * 32;
  const int rb = blockIdx.x * 64;

  short8 wf[2][4];
  #pragma unroll
  for (int cb = 0; cb < 2; ++cb) {
    const int col = colf + cb * 16 + l15;
    #pragma unroll
    for (int kt = 0; kt < 4; ++kt)
      wf[cb][kt] = *(const short8*)(wp + (size_t)col * 128 + kt * 32 + g * 8);
  }
  float bia[2][4];
  #pragma unroll
  for (int cb = 0; cb < 2; ++cb)
    #pragma unroll
    for (int j = 0; j < 4; ++j)
      bia[cb][j] = bo[colf + cb * 16 + g * 4 + j];

  #pragma unroll
  for (int rg = 0; rg < 4; ++rg) {
    const int r = rb + rg * 16 + l15;
    const int ar = (r < M) ? r : (M - 1);
    short8 a[4];
    #pragma unroll
    for (int kt = 0; kt < 4; ++kt)
      a[kt] = *(const short8*)(A + (size_t)ar * 128 + kt * 32 + g * 8);

    f32x4 accs[2];
    #pragma unroll
    for (int cb = 0; cb < 2; ++cb) {
      f32x4 acc; acc[0] = 0.f; acc[1] = 0.f; acc[2] = 0.f; acc[3] = 0.f;
      #pragma unroll
      for (int kt = 0; kt < 4; ++kt)
        acc = __builtin_amdgcn_mfma_f32_16x16x32_bf16(wf[cb][kt], a[kt], acc, 0, 0, 0);
      accs[cb] = acc;
    }

    if (r < M) {
      const float gr = gate[r];
      #pragma unroll
      for (int cb = 0; cb < 2; ++cb) {
        const int c0 = colf + cb * 16 + g * 4;
        const float4 xv = *(const float4*)(xin + (size_t)r * 128 + c0);
        float4 res;
        res.x = gr * xv.x + (1.f - gr) * (accs[cb][0] + bia[cb][0]);
        res.y = gr * xv.y + (1.f - gr) * (accs[cb][1] + bia[cb][1]);
        res.z = gr * xv.z + (1.f - gr) * (accs[cb][2] + bia[cb][2]);
        res.w = gr * xv.w + (1.f - gr) * (accs[cb][3] + bia[cb][3]);
        *(float4*)(out + (size_t)r * 128 + c0) = res;
      }
    }
  }
}

// ================= fused CSR attention + node epilogue, 4-edge unrolled =================
__global__ __launch_bounds__(256) void csr_attn(
    const int* __restrict__ rowstart, const int2* __restrict__ rec,
    const unsigned short* __restrict__ e,
    const unsigned short* __restrict__ q, const unsigned short* __restrict__ k,
    const unsigned short* __restrict__ v, const unsigned short* __restrict__ xr,
    const float* __restrict__ Wb, const float* __restrict__ lng, const float* __restrict__ lnb,
    const unsigned short* __restrict__ prev, unsigned short* __restrict__ hout)
{
  const int n = blockIdx.x * 4 + (threadIdx.x >> 6);
  if (n >= NN) return;
  const int lane = threadIdx.x & 63;
  const int d0 = lane * 2;
  const size_t base = (size_t)n * 128 + d0;

  const unsigned int qp = *(const unsigned int*)(q + base);
  const float q0 = bf2f(qp & 0xffff), q1 = bf2f(qp >> 16);

  float acc0 = 0.f, acc1 = 0.f, den = 0.f;
  const int s = rowstart[n], eend = rowstart[n + 1];
  const float scale = 0.17677669529663687f;   // 1/sqrt(32)

  int pos = s;
  // ---- 4-wide main loop: 12 gathers in flight, 4 interleaved reduce chains ----
  for (; pos + 3 < eend; pos += 4) {
    const int2 r0 = rec[pos], r1 = rec[pos + 1], r2 = rec[pos + 2], r3 = rec[pos + 3];
    const unsigned int kp0 = *(const unsigned int*)(k + (size_t)r0.x * 128 + d0);
    const unsigned int kp1 = *(const unsigned int*)(k + (size_t)r1.x * 128 + d0);
    const unsigned int kp2 = *(const unsigned int*)(k + (size_t)r2.x * 128 + d0);
    const unsigned int kp3 = *(const unsigned int*)(k + (size_t)r3.x * 128 + d0);
    const unsigned int ep0 = *(const unsigned int*)(e + (size_t)r0.y * 128 + d0);
    const unsigned int ep1 = *(const unsigned int*)(e + (size_t)r1.y * 128 + d0);
    const unsigned int ep2 = *(const unsigned int*)(e + (size_t)r2.y * 128 + d0);
    const unsigned int ep3 = *(const unsigned int*)(e + (size_t)r3.y * 128 + d0);
    const unsigned int vp0 = *(const unsigned int*)(v + (size_t)r0.x * 128 + d0);
    const unsigned int vp1 = *(const unsigned int*)(v + (size_t)r1.x * 128 + d0);
    const unsigned int vp2 = *(const unsigned int*)(v + (size_t)r2.x * 128 + d0);
    const unsigned int vp3 = *(const unsigned int*)(v + (size_t)r3.x * 128 + d0);

    const float e00 = bf2f(ep0 & 0xffff), e01 = bf2f(ep0 >> 16);
    const float e10 = bf2f(ep1 & 0xffff), e11 = bf2f(ep1 >> 16);
    const float e20 = bf2f(ep2 & 0xffff), e21 = bf2f(ep2 >> 16);
    const float e30 = bf2f(ep3 & 0xffff), e31 = bf2f(ep3 >> 16);

    float d0_ = q0 * (bf2f(kp0 & 0xffff) + e00) + q1 * (bf2f(kp0 >> 16) + e01);
    float d1_ = q0 * (bf2f(kp1 & 0xffff) + e10) + q1 * (bf2f(kp1 >> 16) + e11);
    float d2_ = q0 * (bf2f(kp2 & 0xffff) + e20) + q1 * (bf2f(kp2 >> 16) + e21);
    float d3_ = q0 * (bf2f(kp3 & 0xffff) + e30) + q1 * (bf2f(kp3 >> 16) + e31);

    d0_ += __shfl_xor(d0_, 1, 64); d1_ += __shfl_xor(d1_, 1, 64);
    d2_ += __shfl_xor(d2_, 1, 64); d3_ += __shfl_xor(d3_, 1, 64);
    d0_ += __shfl_xor(d0_, 2, 64); d1_ += __shfl_xor(d1_, 2, 64);
    d2_ += __shfl_xor(d2_, 2, 64); d3_ += __shfl_xor(d3_, 2, 64);
    d0_ += __shfl_xor(d0_, 4, 64); d1_ += __shfl_xor(d1_, 4, 64);
    d2_ += __shfl_xor(d2_, 4, 64); d3_ += __shfl_xor(d3_, 4, 64);
    d0_ += __shfl_xor(d0_, 8, 64); d1_ += __shfl_xor(d1_, 8, 64);
    d2_ += __shfl_xor(d2_, 8, 64); d3_ += __shfl_xor(d3_, 8, 64);

    const float p0 = expf(d0_ * scale);
    const float p1 = expf(d1_ * scale);
    const float p2 = expf(d2_ * scale);
    const float p3 = expf(d3_ * scale);

    acc0 += p0 * (bf2f(vp0 & 0xffff) + e00) + p1 * (bf2f(vp1 & 0xffff) + e10)
          + p2 * (bf2f(vp2 & 0xffff) + e20) + p3 * (bf2f(vp3 & 0xffff) + e30);
    acc1 += p0 * (bf2f(vp0 >> 16) + e01) + p1 * (bf2f(vp1 >> 16) + e11)
          + p2 * (bf2f(vp2 >> 16) + e21) + p3 * (bf2f(vp3 >> 16) + e31);
    den  += (p0 + p1) + (p2 + p3);
  }
  // ---- tail ----
  for (; pos < eend; ++pos) {
    const int2 rA = rec[pos];
    const unsigned int kpA = *(const unsigned int*)(k + (size_t)rA.x * 128 + d0);
    const unsigned int epA = *(const unsigned int*)(e + (size_t)rA.y * 128 + d0);
    const unsigned int vpA = *(const unsigned int*)(v + (size_t)rA.x * 128 + d0);
    const float eA0 = bf2f(epA & 0xffff), eA1 = bf2f(epA >> 16);
    float dotA = q0 * (bf2f(kpA & 0xffff) + eA0) + q1 * (bf2f(kpA >> 16) + eA1);
    dotA += __shfl_xor(dotA, 1, 64);
    dotA += __shfl_xor(dotA, 2, 64);
    dotA += __shfl_xor(dotA, 4, 64);
    dotA += __shfl_xor(dotA, 8, 64);
    const float pA = expf(dotA * scale);
    acc0 += pA * (bf2f(vpA & 0xffff) + eA0);
    acc1 += pA * (bf2f(vpA >> 16) + eA1);
    den  += pA;
  }

  const float dinv = 1.f / (den + 1e-16f);
  const float o0 = acc0 * dinv, o1 = acc1 * dinv;

  const float x0 = bf2f(xr[base]), x1 = bf2f(xr[base + 1]);
  float sb = o0 * Wb[d0] + o1 * Wb[d0 + 1]
           + x0 * Wb[128 + d0] + x1 * Wb[129 + d0]
           + (o0 - x0) * Wb[256 + d0] + (o1 - x1) * Wb[257 + d0];
  #pragma unroll
  for (int off = 32; off >= 1; off >>= 1) sb += __shfl_xor(sb, off, 64);
  const float beta = 1.f / (1.f + expf(-sb));

  float y0 = beta * x0 + (1.f - beta) * o0;
  float y1 = beta * x1 + (1.f - beta) * o1;
  y0 = 0.5f * y0 * (1.f + erff(y0 * 0.7071067811865475f));
  y1 = 0.5f * y1 * (1.f + erff(y1 * 0.7071067811865475f));

  float mu = y0 + y1;
  #pragma unroll
  for (int off = 32; off >= 1; off >>= 1) mu += __shfl_xor(mu, off, 64);
  mu *= (1.f / 128.f);
  float dv0 = y0 - mu, dv1 = y1 - mu;
  float var = dv0 * dv0 + dv1 * dv1;
  #pragma unroll
  for (int off = 32; off >= 1; off >>= 1) var += __shfl_xor(var, off, 64);
  var *= (1.f / 128.f);
  const float rs = rsqrtf(var + 1e-5f);

  float h0 = dv0 * rs * lng[d0] + lnb[d0];
  float h1 = dv1 * rs * lng[d0 + 1] + lnb[d0 + 1];
  if (prev) { h0 += bf2f(prev[base]); h1 += bf2f(prev[base + 1]); }
  unsigned int packed = (unsigned int)f2bf(h0) | ((unsigned int)f2bf(h1) << 16);
  *(unsigned int*)(hout + base) = packed;
}

// ================= gate =================
__global__ __launch_bounds__(256) void gate_kernel(
    const float* __restrict__ x, const float* __restrict__ Wg,
    const float* __restrict__ bg, float* __restrict__ g)
{
  const int row = blockIdx.x * 4 + (threadIdx.x >> 6);
  const int lane = threadIdx.x & 63;
  const size_t base = (size_t)row * 128 + lane * 2;
  float s = x[base] * Wg[lane * 2] + x[base + 1] * Wg[lane * 2 + 1];
  #pragma unroll
  for (int off = 32; off >= 1; off >>= 1) s += __shfl_xor(s, off, 64);
  g[row] = 1.f / (1.f + expf(-(s + bg[0])));
}

extern "C" void kernel_launch(void* const* d_in, const int* in_sizes, int n_in,
                              void* d_out, int out_size, void* d_ws, size_t ws_size,
                              hipStream_t stream)
{
  const float* x  = (const float*)d_in[0];
  const int*   ei = (const int*)d_in[1];
  const float* ea = (const float*)d_in[2];
  const float* Wq = (const float*)d_in[3];
  const float* bq = (const float*)d_in[4];
  const float* Wk = (const float*)d_in[5];
  const float* bk = (const float*)d_in[6];
  const float* Wv = (const float*)d_in[7];
  const float* bv = (const float*)d_in[8];
  const float* We = (const float*)d_in[9];
  const float* Ws = (const float*)d_in[10];
  const float* bs = (const float*)d_in[11];
  const float* Wb = (const float*)d_in[12];
  const float* lng= (const float*)d_in[13];
  const float* lnb= (const float*)d_in[14];
  const float* Wo = (const float*)d_in[15];
  const float* bo = (const float*)d_in[16];
  const float* Wg = (const float*)d_in[17];
  const float* bg = (const float*)d_in[18];
  float* outp = (float*)d_out;

  char* p = (char*)d_ws;
  auto take = [&](size_t b) -> char* { char* r = p; p += (b + 255) & ~(size_t)255; return r; };
  unsigned short* wT = (unsigned short*)take((size_t)11 * 16384 * 2);
  unsigned short* q  = (unsigned short*)take((size_t)NN * 128 * 2);
  unsigned short* k  = (unsigned short*)take((size_t)NN * 128 * 2);
  unsigned short* v  = (unsigned short*)take((size_t)NN * 128 * 2);
  unsigned short* xr = (unsigned short*)take((size_t)NN * 128 * 2);
  unsigned short* h1 = (unsigned short*)take((size_t)NN * 128 * 2);
  unsigned short* hs = (unsigned short*)take((size_t)NN * 128 * 2);
  float* gbuf = (float*)take((size_t)NN * 4);
  int* deg      = (int*)take((size_t)NN * 4);
  int* rowstart = (int*)take((size_t)(NN + 1) * 4);
  int* cursor   = (int*)take((size_t)NN * 4);
  int* bsum     = (int*)take((size_t)128 * 4);
  int2* rec     = (int2*)take((size_t)NE * 8);
  unsigned short* e0 = (unsigned short*)take((size_t)NE * 128 * 2);
  size_t used = (size_t)(p - (char*)d_ws);
  const bool dual = (used + (size_t)NE * 128 * 2) <= ws_size;
  unsigned short* e1 = dual ? (unsigned short*)take((size_t)NE * 128 * 2) : e0;

  const int SCAN_BLOCKS = (NN + 1023) / 1024;   // 98
  const int NTILE_E  = (NE + 127) / 128;        // 6250   (gemm_lds: 128 rows/block)
  const int NTILE_N  = (NN + 127) / 128;        // 782    (gemm_lds: 128 rows/block)
  const int NTILE_N64 = (NN + 63) / 64;         // 1563   (final_rs: 64 rows/block)

  // ---- CSR build ----
  hipMemsetAsync(deg, 0, (size_t)NN * 4, stream);
  hist_k<<<(NE + 255) / 256, 256, 0, stream>>>(ei, deg);
  scan1<<<SCAN_BLOCKS, 256, 0, stream>>>(deg, bsum);
  scan2<<<1, 64, 0, stream>>>(bsum, SCAN_BLOCKS, rowstart);
  scan3<<<SCAN_BLOCKS, 256, 0, stream>>>(deg, bsum, rowstart, cursor);
  scatter_k<<<(NE + 255) / 256, 256, 0, stream>>>(ei, cursor, rec);

  // ---- weights + edge projection (coalesced, edge order) ----
  conv_w<<<704, 256, 0, stream>>>(Wq, Wk, Wv, Ws, We, Wo, wT);
  if (dual) {
    gemm_lds<0,0,2><<<NTILE_E, 256, 0, stream>>>(ea, wT, 8, 9, nullptr, nullptr, e0, e1, NE);
  } else {
    gemm_lds<0,0,1><<<NTILE_E, 256, 0, stream>>>(ea, wT, 8, 8, nullptr, nullptr, e0, e0, NE);
  }

  // ---- layer 1 ----
  gemm_lds<0,1,2><<<NTILE_N, 256, 0, stream>>>(x, wT, 0, 1, bq, bk, q, k, NN);
  gemm_lds<0,1,2><<<NTILE_N, 256, 0, stream>>>(x, wT, 2, 3, bv, bs, v, xr, NN);
  csr_attn<<<25000, 256, 0, stream>>>(rowstart, rec, e0, q, k, v, xr, Wb, lng, lnb, nullptr, h1);

  // ---- layer 2 ----
  if (!dual) gemm_lds<0,0,1><<<NTILE_E, 256, 0, stream>>>(ea, wT, 9, 9, nullptr, nullptr, e0, e0, NE);
  gemm_lds<1,1,2><<<NTILE_N, 256, 0, stream>>>(h1, wT, 4, 5, bq + 128, bk + 128, q, k, NN);
  gemm_lds<1,1,2><<<NTILE_N, 256, 0, stream>>>(h1, wT, 6, 7, bv + 128, bs + 128, v, xr, NN);
  csr_attn<<<25000, 256, 0, stream>>>(rowstart, rec, e1, q, k, v, xr, Wb + 384, lng + 128, lnb + 128, h1, hs);

  // ---- final ----
  gate_kernel<<<25000, 256, 0, stream>>>(x, Wg, bg, gbuf);
  final_rs<<<NTILE_N64, 256, 0, stream>>>(hs, wT + (size_t)10 * 16384, bo, x, gbuf, outp, NN);
}